// Round 1
// baseline (67572.577 us; speedup 1.0000x reference)
//
#include <hip/hip_runtime.h>
#include <hip/hip_cooperative_groups.h>

namespace cg = cooperative_groups;

#define Bsz 64
#define Tn 256
#define Hn 512
#define Ln 4
#define FUTn 64
#define Gn 2048          // 4*H
#define TTn 320          // T + FUT

// Persistent state in device globals (avoids ws_size assumptions).
// h double-buffered by timestep parity: [2][L][H][B]; c in-place: [L][H][B].
__device__ float g_h[2 * Ln * Hn * Bsz];
__device__ float g_c[Ln * Hn * Bsz];

__device__ __forceinline__ float sigm(float x) { return 1.0f / (1.0f + expf(-x)); }

__device__ __forceinline__ void fma4(float4& a, const float4 h, const float w) {
    a.x = fmaf(h.x, w, a.x);
    a.y = fmaf(h.y, w, a.y);
    a.z = fmaf(h.z, w, a.z);
    a.w = fmaf(h.w, w, a.w);
}

// 256-length dot-product chunk: acc[b..b+3] += sum_k w[k] * h[k][b..b+3]
__device__ __forceinline__ float4 dot256(const float* __restrict__ wr,
                                         const float* __restrict__ hp,
                                         float4 acc) {
#pragma unroll 4
    for (int k = 0; k < 256; k += 4) {
        float4 w  = *(const float4*)(wr + k);
        float4 h0 = *(const float4*)(hp + 0 * Bsz);
        float4 h1 = *(const float4*)(hp + 1 * Bsz);
        float4 h2 = *(const float4*)(hp + 2 * Bsz);
        float4 h3 = *(const float4*)(hp + 3 * Bsz);
        hp += 4 * Bsz;
        fma4(acc, h0, w.x);
        fma4(acc, h1, w.y);
        fma4(acc, h2, w.z);
        fma4(acc, h3, w.w);
    }
    return acc;
}

__global__ __launch_bounds__(256)
void lstm_seq(const float* __restrict__ iput,   // [B][T]
              const float* __restrict__ Wih0,   // [2048][1]
              const float* __restrict__ Wih,    // [3][2048][512]
              const float* __restrict__ Whh,    // [4][2048][512]
              const float* __restrict__ bih,    // [4][2048]
              const float* __restrict__ bhh,    // [4][2048]
              const float* __restrict__ Wlin,   // [1][512]
              const float* __restrict__ blin,   // [1]
              float* __restrict__ out)          // [B][320]
{
    cg::grid_group grid = cg::this_grid();
    const int bi  = blockIdx.x;     // 0..255  -> owns j in {2*bi, 2*bi+1}
    const int tid = threadIdx.x;    // 0..255
    const int bg  = tid & 15;       // batch group: b4 = bg*4
    const int gq  = (tid >> 4) & 7; // (j_local<<2)|type
    const int kh  = tid >> 7;       // reduction half 0/1
    const int jl  = gq >> 2;
    const int ty  = gq & 3;
    const int jglob = bi * 2 + jl;
    const int g     = ty * Hn + jglob;   // gate column in [0,2048)
    const int b4    = bg * 4;

    __shared__ __align__(16) float part[8][2][Bsz]; // partial gates
    __shared__ float rpart[4][Bsz];                 // readout partials
    __shared__ float xs[Bsz];                       // feedback input

    // zero-init state (harness poisons buffers with 0xAA)
    for (int i = bi * 256 + tid; i < 2 * Ln * Hn * Bsz; i += 256 * 256) g_h[i] = 0.0f;
    for (int i = bi * 256 + tid; i < Ln * Hn * Bsz; i += 256 * 256) g_c[i] = 0.0f;
    grid.sync();

    const float blin0 = blin[0];

    for (int t = 0; t < TTn; ++t) {
        const int ci = t & 1;
        float* hcur        = g_h + ci * (Ln * Hn * Bsz);
        const float* hprev = g_h + (ci ^ 1) * (Ln * Hn * Bsz);

        // ---- readout of timestep t-1 (folded into this phase; no extra sync)
        // warmup: one (rotating) block computes+writes it; future phase: every
        // block computes it redundantly because all need x = out(t-1).
        if (t > 0) {
            const int owner = (t - 1) & 255;
            if (t >= Tn || bi == owner) {
                const float* h3 = hprev + 3 * Hn * Bsz;
                const int b = tid & 63, jq = tid >> 6;
                const float* hp = h3 + jq * 128 * Bsz + b;
                const float* wp = Wlin + jq * 128;
                float r = 0.0f;
#pragma unroll 8
                for (int j = 0; j < 128; ++j) r = fmaf(hp[j * Bsz], wp[j], r);
                rpart[jq][b] = r;
                __syncthreads();
                if (tid < 64) {
                    float x = rpart[0][b] + rpart[1][b] + rpart[2][b] + rpart[3][b] + blin0;
                    xs[b] = x;
                    if (bi == owner) out[b * TTn + (t - 1)] = x;
                }
                __syncthreads();
            }
        }

        // ---- 4 sequential layer phases, one grid sync each
        for (int lyr = 0; lyr < Ln; ++lyr) {
            float4 acc = make_float4(0.f, 0.f, 0.f, 0.f);
            const float* hsame = hprev + lyr * Hn * Bsz;

            if (lyr > 0) {  // input contribution from layer lyr-1 at time t
                const float* hin = hcur + (lyr - 1) * Hn * Bsz;
                const float* wr  = Wih + (((lyr - 1) * Gn + g) * Hn) + kh * 256;
                const float* hp  = hin + (kh * 256) * Bsz + b4;
                acc = dot256(wr, hp, acc);
            }
            {   // hidden-hidden contribution (h at t-1)
                const float* wr = Whh + ((lyr * Gn + g) * Hn) + kh * 256;
                const float* hp = hsame + (kh * 256) * Bsz + b4;
                acc = dot256(wr, hp, acc);
            }
            *(float4*)&part[gq][kh][b4] = acc;
            __syncthreads();

            if (tid < 128) {  // finalize: combine halves, add biases, LSTM update
                const int jl2 = tid >> 6, b = tid & 63;
                const int jg2 = bi * 2 + jl2;
                float gv[4];
#pragma unroll
                for (int q = 0; q < 4; ++q) {
                    const int gg = q * Hn + jg2;
                    float v = part[(jl2 << 2) | q][0][b] + part[(jl2 << 2) | q][1][b];
                    v += bih[lyr * Gn + gg] + bhh[lyr * Gn + gg];
                    gv[q] = v;
                }
                if (lyr == 0) {
                    const float xv = (t < Tn) ? iput[b * Tn + t] : xs[b];
#pragma unroll
                    for (int q = 0; q < 4; ++q) gv[q] = fmaf(xv, Wih0[q * Hn + jg2], gv[q]);
                }
                const float i_ = sigm(gv[0]);
                const float f_ = sigm(gv[1]);
                const float g_ = tanhf(gv[2]);
                const float o_ = sigm(gv[3]);
                float* cp = g_c + (lyr * Hn + jg2) * Bsz + b;
                const float c2 = fmaf(f_, *cp, i_ * g_);
                *cp = c2;
                hcur[(lyr * Hn + jg2) * Bsz + b] = o_ * tanhf(c2);
            }
            grid.sync();
        }
    }

    // ---- final readout: out(:, 319) from h3 of t=319
    if (bi == 0) {
        const float* h3 = g_h + ((TTn - 1) & 1) * (Ln * Hn * Bsz) + 3 * Hn * Bsz;
        const int b = tid & 63, jq = tid >> 6;
        const float* hp = h3 + jq * 128 * Bsz + b;
        const float* wp = Wlin + jq * 128;
        float r = 0.0f;
#pragma unroll 8
        for (int j = 0; j < 128; ++j) r = fmaf(hp[j * Bsz], wp[j], r);
        rpart[jq][b] = r;
        __syncthreads();
        if (tid < 64) out[b * TTn + (TTn - 1)] = rpart[0][b] + rpart[1][b] + rpart[2][b] + rpart[3][b] + blin0;
    }
}

extern "C" void kernel_launch(void* const* d_in, const int* in_sizes, int n_in,
                              void* d_out, int out_size, void* d_ws, size_t ws_size,
                              hipStream_t stream) {
    const float* iput = (const float*)d_in[0];
    const float* Wih0 = (const float*)d_in[1];
    const float* Wih  = (const float*)d_in[2];
    const float* Whh  = (const float*)d_in[3];
    const float* bih  = (const float*)d_in[4];
    const float* bhh  = (const float*)d_in[5];
    const float* Wlin = (const float*)d_in[6];
    const float* blin = (const float*)d_in[7];
    float* out = (float*)d_out;

    void* args[] = {&iput, &Wih0, &Wih, &Whh, &bih, &bhh, &Wlin, &blin, &out};
    hipLaunchCooperativeKernel((const void*)lstm_seq, dim3(256), dim3(256), args, 0, stream);
}

// Round 2
// 52264.374 us; speedup vs baseline: 1.2929x; 1.2929x over previous
//
#include <hip/hip_runtime.h>
#include <hip/hip_cooperative_groups.h>

namespace cg = cooperative_groups;

#define Bsz 64
#define Tn 256
#define Hn 512
#define Ln 4
#define Gn 2048          // 4*H
#define TTn 320          // T + FUT

// ---- dynamic LDS layout (float offsets) ----
#define OFF_WHH 0                               // [4][8][512] hidden->gates rows
#define OFF_WIH (OFF_WHH + Ln * 8 * Hn)         // [3][8][512] input->gates rows
#define OFF_PART (OFF_WIH + (Ln - 1) * 8 * Hn)  // [16][8][64] k-group partials
#define OFF_GSUM (OFF_PART + 16 * 8 * 64)       // [8][64] summed gates
#define OFF_BS   (OFF_GSUM + 8 * 64)            // [4][8] bih+bhh
#define OFF_W0   (OFF_BS + Ln * 8)              // [8] layer-0 input weights
#define OFF_WLIN (OFF_W0 + 8)                   // [512] readout weights
#define OFF_RP   (OFF_WLIN + Hn)                // [4][64] readout partials
#define OFF_XS   (OFF_RP + 4 * 64)              // [64] feedback input
#define SMEM_FLOATS (OFF_XS + 64)
#define SMEM_BYTES (SMEM_FLOATS * 4)

// persistent state: h double-buffered by timestep parity, c in place
__device__ float g_h[2 * Ln * Hn * Bsz];
__device__ float g_c[Ln * Hn * Bsz];

__device__ __forceinline__ float sigm(float x) { return 1.0f / (1.0f + expf(-x)); }

__device__ __forceinline__ void fma4(float4& a, const float4 h, const float w) {
    a.x = fmaf(h.x, w, a.x);
    a.y = fmaf(h.y, w, a.y);
    a.z = fmaf(h.z, w, a.z);
    a.w = fmaf(h.w, w, a.w);
}

// Partial GEMM: acc[r] += sum_{k in thread's 32-k chunk} w[r][k] * h[k][b4..b4+3]
// k iterated with per-kg rotation (rot) to avoid 4-way LDS bank conflicts.
__device__ __forceinline__ void gemm_part(const float* __restrict__ w,  // LDS [8][512]
                                          const float* __restrict__ h, // global [512][64]
                                          int k0, int rot, int b4, float4* acc) {
#pragma unroll 2
    for (int c = 0; c < 8; ++c) {
        const int k = k0 + ((c * 4 + rot) & 31);
        const float* hp = h + k * Bsz + b4;
        const float4 h0 = *(const float4*)(hp);
        const float4 h1 = *(const float4*)(hp + Bsz);
        const float4 h2 = *(const float4*)(hp + 2 * Bsz);
        const float4 h3 = *(const float4*)(hp + 3 * Bsz);
#pragma unroll
        for (int r = 0; r < 8; ++r) {
            const float4 wv = *(const float4*)(w + r * Hn + k);
            fma4(acc[r], h0, wv.x);
            fma4(acc[r], h1, wv.y);
            fma4(acc[r], h2, wv.z);
            fma4(acc[r], h3, wv.w);
        }
    }
}

__global__ __launch_bounds__(256, 1)
void lstm_seq(const float* __restrict__ iput,   // [B][T]
              const float* __restrict__ Wih0,   // [2048]
              const float* __restrict__ Wih,    // [3][2048][512]
              const float* __restrict__ Whh,    // [4][2048][512]
              const float* __restrict__ bih,    // [4][2048]
              const float* __restrict__ bhh,    // [4][2048]
              const float* __restrict__ Wlin,   // [512]
              const float* __restrict__ blin,   // [1]
              float* __restrict__ out)          // [B][320]
{
    cg::grid_group grid = cg::this_grid();
    extern __shared__ float sm[];

    const int bi  = blockIdx.x;      // owns columns j in {2*bi, 2*bi+1}
    const int tid = threadIdx.x;
    const int bg  = tid & 15;        // batch group (4 per thread)
    const int kg  = tid >> 4;        // k group (32 per thread)
    const int b4  = bg * 4;
    const int k0  = kg * 32;
    const int rot = (kg & 3) * 8;    // bank-conflict-avoiding rotation

    // ---- one-time: stage this block's weight slice into LDS ----
    // row r = (jl<<2)|q maps to gate row q*512 + (bi*2 + jl)
    for (int i = tid; i < Ln * 8 * Hn; i += 256) {
        const int lyr = i >> 12, rem = i & 4095, r = rem >> 9, k = rem & 511;
        sm[OFF_WHH + i] = Whh[((size_t)(lyr * Gn + (r & 3) * Hn + bi * 2 + (r >> 2))) * Hn + k];
    }
    for (int i = tid; i < (Ln - 1) * 8 * Hn; i += 256) {
        const int lyr = i >> 12, rem = i & 4095, r = rem >> 9, k = rem & 511;
        sm[OFF_WIH + i] = Wih[((size_t)(lyr * Gn + (r & 3) * Hn + bi * 2 + (r >> 2))) * Hn + k];
    }
    if (tid < Ln * 8) {
        const int lyr = tid >> 3, r = tid & 7;
        const int gg = lyr * Gn + (r & 3) * Hn + bi * 2 + (r >> 2);
        sm[OFF_BS + tid] = bih[gg] + bhh[gg];
    }
    if (tid < 8) sm[OFF_W0 + tid] = Wih0[(tid & 3) * Hn + bi * 2 + (tid >> 2)];
    for (int i = tid; i < Hn; i += 256) sm[OFF_WLIN + i] = Wlin[i];

    // zero-init persistent state (buffers poisoned by harness)
    for (int i = bi * 256 + tid; i < 2 * Ln * Hn * Bsz; i += 256 * 256) g_h[i] = 0.0f;
    for (int i = bi * 256 + tid; i < Ln * Hn * Bsz; i += 256 * 256) g_c[i] = 0.0f;
    grid.sync();

    const float blin0 = blin[0];

    for (int t = 0; t < TTn; ++t) {
        const int ci = t & 1;
        float* hcur        = g_h + ci * (Ln * Hn * Bsz);
        const float* hprev = g_h + (ci ^ 1) * (Ln * Hn * Bsz);

        // ---- readout of t-1 folded into this phase (no extra grid sync)
        if (t > 0) {
            const int owner = (t - 1) & 255;
            if (t >= Tn || bi == owner) {
                const float* h3 = hprev + 3 * Hn * Bsz;
                const int b = tid & 63, jq = tid >> 6;
                const float* hp = h3 + jq * 128 * Bsz + b;
                const float* wp = sm + OFF_WLIN + jq * 128;
                float r = 0.0f;
#pragma unroll 8
                for (int j = 0; j < 128; ++j) r = fmaf(hp[j * Bsz], wp[j], r);
                sm[OFF_RP + jq * 64 + b] = r;
                __syncthreads();
                if (tid < 64) {
                    const float x = sm[OFF_RP + b] + sm[OFF_RP + 64 + b] +
                                    sm[OFF_RP + 128 + b] + sm[OFF_RP + 192 + b] + blin0;
                    sm[OFF_XS + b] = x;
                    if (bi == owner) out[b * TTn + (t - 1)] = x;
                }
                __syncthreads();
            }
        }

        // ---- 4 layer phases, one grid sync each
        for (int lyr = 0; lyr < Ln; ++lyr) {
            float4 acc[8];
#pragma unroll
            for (int r = 0; r < 8; ++r) acc[r] = make_float4(0.f, 0.f, 0.f, 0.f);

            if (lyr > 0) {
                gemm_part(sm + OFF_WIH + (lyr - 1) * 8 * Hn,
                          hcur + (lyr - 1) * Hn * Bsz, k0, rot, b4, acc);
            }
            gemm_part(sm + OFF_WHH + lyr * 8 * Hn,
                      hprev + lyr * Hn * Bsz, k0, rot, b4, acc);

#pragma unroll
            for (int r = 0; r < 8; ++r)
                *(float4*)&sm[OFF_PART + (kg * 8 + r) * 64 + b4] = acc[r];
            __syncthreads();

            // stage A: reduce 16 k-partials per gate value (2 outputs/thread)
            {
                int o = tid;
#pragma unroll
                for (int s = 0; s < 2; ++s, o += 256) {
                    const int r = o >> 6, b = o & 63;
                    float v = sm[OFF_BS + lyr * 8 + r];
#pragma unroll
                    for (int g2 = 0; g2 < 16; ++g2)
                        v += sm[OFF_PART + (g2 * 8 + r) * 64 + b];
                    if (lyr == 0) {
                        const float xv = (t < Tn) ? iput[b * Tn + t] : sm[OFF_XS + b];
                        v = fmaf(xv, sm[OFF_W0 + r], v);
                    }
                    sm[OFF_GSUM + o] = v;
                }
            }
            __syncthreads();

            // stage B: LSTM elementwise update (128 threads: 2 cols x 64 batch)
            if (tid < 128) {
                const int jl = tid >> 6, b = tid & 63;
                const int jg = bi * 2 + jl;
                const float* gs = sm + OFF_GSUM + jl * 4 * 64;
                const float i_ = sigm(gs[0 * 64 + b]);
                const float f_ = sigm(gs[1 * 64 + b]);
                const float g_ = tanhf(gs[2 * 64 + b]);
                const float o_ = sigm(gs[3 * 64 + b]);
                float* cp = g_c + (lyr * Hn + jg) * Bsz + b;
                const float c2 = fmaf(f_, *cp, i_ * g_);
                *cp = c2;
                hcur[(lyr * Hn + jg) * Bsz + b] = o_ * tanhf(c2);
            }
            grid.sync();
        }
    }

    // ---- final readout: out(:, 319)
    if (bi == 0) {
        const float* h3 = g_h + ((TTn - 1) & 1) * (Ln * Hn * Bsz) + 3 * Hn * Bsz;
        const int b = tid & 63, jq = tid >> 6;
        const float* hp = h3 + jq * 128 * Bsz + b;
        const float* wp = sm + OFF_WLIN + jq * 128;
        float r = 0.0f;
#pragma unroll 8
        for (int j = 0; j < 128; ++j) r = fmaf(hp[j * Bsz], wp[j], r);
        sm[OFF_RP + jq * 64 + b] = r;
        __syncthreads();
        if (tid < 64)
            out[b * TTn + (TTn - 1)] = sm[OFF_RP + b] + sm[OFF_RP + 64 + b] +
                                       sm[OFF_RP + 128 + b] + sm[OFF_RP + 192 + b] + blin0;
    }
}

extern "C" void kernel_launch(void* const* d_in, const int* in_sizes, int n_in,
                              void* d_out, int out_size, void* d_ws, size_t ws_size,
                              hipStream_t stream) {
    const float* iput = (const float*)d_in[0];
    const float* Wih0 = (const float*)d_in[1];
    const float* Wih  = (const float*)d_in[2];
    const float* Whh  = (const float*)d_in[3];
    const float* bih  = (const float*)d_in[4];
    const float* bhh  = (const float*)d_in[5];
    const float* Wlin = (const float*)d_in[6];
    const float* blin = (const float*)d_in[7];
    float* out = (float*)d_out;

    (void)hipFuncSetAttribute((const void*)lstm_seq,
                              hipFuncAttributeMaxDynamicSharedMemorySize, SMEM_BYTES);

    void* args[] = {&iput, &Wih0, &Wih, &Whh, &bih, &bhh, &Wlin, &blin, &out};
    hipLaunchCooperativeKernel((const void*)lstm_seq, dim3(256), dim3(256), args,
                               SMEM_BYTES, stream);
}

// Round 3
// 15831.281 us; speedup vs baseline: 4.2683x; 3.3013x over previous
//
#include <hip/hip_runtime.h>

#define Bsz 64
#define Tn 256
#define Hn 512
#define Ln 4
#define Gn 2048
#define TTn 320
#define NBLK 256
#define NTHR 512
#define HB (Hn * Bsz)
#define LHB (Ln * HB)

// ---- LDS layout (float offsets) ----
#define OFF_WHH  0                                // [4][8][512]
#define OFF_WIH  (OFF_WHH + Ln * 8 * Hn)          // [3][8][512]
#define OFF_PART (OFF_WIH + (Ln - 1) * 8 * Hn)    // [8 waves][8 r][64 b]
#define OFF_GSUM (OFF_PART + 8 * 8 * Bsz)         // [8][64]
#define OFF_BS   (OFF_GSUM + 8 * Bsz)             // [4][8]
#define OFF_W0   (OFF_BS + Ln * 8)                // [8]
#define OFF_WLIN (OFF_W0 + 8)                     // [512]
#define OFF_RP   (OFF_WLIN + Hn)                  // [8][64] (also reused as tmp)
#define OFF_XS   (OFF_RP + 8 * Bsz)               // [64]
#define OFF_C    (OFF_XS + Bsz)                   // [4][2][64]
#define SMEM_FLOATS (OFF_C + Ln * 2 * Bsz)
#define SMEM_BYTES (SMEM_FLOATS * 4)              // ~139.7 KB

__device__ float g_h[2 * LHB];        // h double-buffered by t parity
__device__ float g_hist[Tn * HB];     // h3 history for batched warmup readout (32MB)
__device__ float g_p[Bsz * NBLK];     // distributed readout partials [b][block]
__device__ float g_xsg[Bsz];          // x seed for t=256
__device__ uint32_t g_cnt[8 * 32];    // barrier counters (128B apart)
__device__ uint32_t g_master;
__device__ uint32_t g_flag;

__device__ __forceinline__ float sigm(float x) { return 1.0f / (1.0f + expf(-x)); }

__device__ __forceinline__ void fma4(float4& a, const float4 h, const float w) {
    a.x = fmaf(h.x, w, a.x);
    a.y = fmaf(h.y, w, a.y);
    a.z = fmaf(h.z, w, a.z);
    a.w = fmaf(h.w, w, a.w);
}

__device__ __forceinline__ void st_agent(float* p, float v) {
    __hip_atomic_store(p, v, __ATOMIC_RELAXED, __HIP_MEMORY_SCOPE_AGENT);
}

// 2-level sense-reversing grid barrier; self-resetting (replay-safe).
__device__ __forceinline__ void gbar(int bi, int tid, uint32_t& sense) {
    __syncthreads();   // drains each wave's vmem before s_barrier
    if (tid == 0) {
        sense ^= 1u;
        __builtin_amdgcn_fence(__ATOMIC_RELEASE, "agent");
        uint32_t old = __hip_atomic_fetch_add(&g_cnt[(bi & 7) * 32], 1u,
                           __ATOMIC_RELAXED, __HIP_MEMORY_SCOPE_AGENT);
        if (old == 31u) {
            uint32_t old2 = __hip_atomic_fetch_add(&g_master, 1u,
                           __ATOMIC_RELAXED, __HIP_MEMORY_SCOPE_AGENT);
            if (old2 == 7u) {   // last block of all: reset, then flip flag
#pragma unroll
                for (int q = 0; q < 8; ++q)
                    __hip_atomic_store(&g_cnt[q * 32], 0u, __ATOMIC_RELAXED,
                                       __HIP_MEMORY_SCOPE_AGENT);
                __hip_atomic_store(&g_master, 0u, __ATOMIC_RELAXED,
                                   __HIP_MEMORY_SCOPE_AGENT);
                __hip_atomic_store(&g_flag, sense, __ATOMIC_RELEASE,
                                   __HIP_MEMORY_SCOPE_AGENT);
            }
        }
        while (__hip_atomic_load(&g_flag, __ATOMIC_RELAXED,
                                 __HIP_MEMORY_SCOPE_AGENT) != sense)
            __builtin_amdgcn_s_sleep(2);
        __builtin_amdgcn_fence(__ATOMIC_ACQUIRE, "agent");  // inv stale L1/L2
    }
    __syncthreads();
}

// Partial GEMM over this thread's 16-k chunk: acc[r] += w[r][k]*h[k][b4..b4+3]
__device__ __forceinline__ void gemm_part(const float* __restrict__ w,   // LDS [8][512]
                                          const float* __restrict__ h,  // global [512][64]
                                          int k0, int b4, float4* acc) {
#pragma unroll
    for (int c = 0; c < 4; ++c) {
        const int k = k0 + c * 4;
        const float* hp = h + (size_t)k * Bsz + b4;
        const float4 h0 = *(const float4*)(hp);
        const float4 h1 = *(const float4*)(hp + Bsz);
        const float4 h2 = *(const float4*)(hp + 2 * Bsz);
        const float4 h3 = *(const float4*)(hp + 3 * Bsz);
#pragma unroll
        for (int r = 0; r < 8; ++r) {
            const float4 wv = *(const float4*)(w + r * Hn + k);
            fma4(acc[r], h0, wv.x);
            fma4(acc[r], h1, wv.y);
            fma4(acc[r], h2, wv.z);
            fma4(acc[r], h3, wv.w);
        }
    }
}

__global__ __launch_bounds__(NTHR, 1)
void lstm_seq(const float* __restrict__ iput,   // [B][T]
              const float* __restrict__ Wih0,   // [2048]
              const float* __restrict__ Wih,    // [3][2048][512]
              const float* __restrict__ Whh,    // [4][2048][512]
              const float* __restrict__ bih,    // [4][2048]
              const float* __restrict__ bhh,    // [4][2048]
              const float* __restrict__ Wlin,   // [512]
              const float* __restrict__ blin,   // [1]
              float* __restrict__ out)          // [B][320]
{
    extern __shared__ float sm[];
    const int bi  = blockIdx.x;
    const int tid = threadIdx.x;
    const int bg  = tid & 15;
    const int kg  = tid >> 4;        // 0..31, k-chunk of 16
    const int b4  = bg * 4;
    const int k0  = kg * 16;
    const int wv_ = tid >> 6;        // wave id 0..7

    uint32_t sense = 0;
    if (tid == 0)
        sense = __hip_atomic_load(&g_flag, __ATOMIC_RELAXED, __HIP_MEMORY_SCOPE_AGENT);

    // ---- stage weights into LDS (row r=(jl<<2)|q -> gate row q*512+bi*2+jl)
    for (int i = tid; i < Ln * 8 * Hn; i += NTHR) {
        const int lyr = i >> 12, rem = i & 4095, r = rem >> 9, k = rem & 511;
        sm[OFF_WHH + i] = Whh[((size_t)(lyr * Gn + (r & 3) * Hn + bi * 2 + (r >> 2))) * Hn + k];
    }
    for (int i = tid; i < (Ln - 1) * 8 * Hn; i += NTHR) {
        const int lyr = i >> 12, rem = i & 4095, r = rem >> 9, k = rem & 511;
        sm[OFF_WIH + i] = Wih[((size_t)(lyr * Gn + (r & 3) * Hn + bi * 2 + (r >> 2))) * Hn + k];
    }
    if (tid < Ln * 8) {
        const int lyr = tid >> 3, r = tid & 7;
        const int gg = lyr * Gn + (r & 3) * Hn + bi * 2 + (r >> 2);
        sm[OFF_BS + tid] = bih[gg] + bhh[gg];
    }
    if (tid < 8) sm[OFF_W0 + tid] = Wih0[(tid & 3) * Hn + bi * 2 + (tid >> 2)];
    for (int i = tid; i < Hn; i += NTHR) sm[OFF_WLIN + i] = Wlin[i];
    for (int i = tid; i < Ln * 2 * Bsz; i += NTHR) sm[OFF_C + i] = 0.0f;

    // zero persistent h (agent stores so all XCDs see zeros on every call)
    for (int i = bi * NTHR + tid; i < 2 * LHB; i += NBLK * NTHR) st_agent(&g_h[i], 0.0f);

    const float blin0 = blin[0];
    gbar(bi, tid, sense);

    // ================= main loop =================
    for (int t = 0; t < TTn; ++t) {
        const bool fut = (t >= Tn);
        const int ci = t & 1;
        float* hcur        = g_h + ci * LHB;
        const float* hprev = g_h + (ci ^ 1) * LHB;

        for (int lyr = 0; lyr < Ln; ++lyr) {
            // future-mode x: wave 0 sums distributed partials (overlaps gemm of other waves)
            if (fut && lyr == 0 && tid < Bsz) {
                float x;
                if (t == Tn) {
                    x = g_xsg[tid];
                } else {
                    const float4* pp = (const float4*)(g_p + tid * NBLK);
                    float4 s4 = make_float4(0.f, 0.f, 0.f, 0.f);
#pragma unroll 16
                    for (int q = 0; q < NBLK / 4; ++q) {
                        const float4 v = pp[q];
                        s4.x += v.x; s4.y += v.y; s4.z += v.z; s4.w += v.w;
                    }
                    x = s4.x + s4.y + s4.z + s4.w + blin0;
                    if (bi == ((t - 1) & 255))
                        st_agent(&out[tid * TTn + (t - 1)], x);
                }
                sm[OFF_XS + tid] = x;
            }

            float4 acc[8];
#pragma unroll
            for (int r = 0; r < 8; ++r) acc[r] = make_float4(0.f, 0.f, 0.f, 0.f);

            if (lyr > 0)
                gemm_part(sm + OFF_WIH + (lyr - 1) * 8 * Hn,
                          hcur + (size_t)(lyr - 1) * HB, k0, b4, acc);
            gemm_part(sm + OFF_WHH + lyr * 8 * Hn,
                      hprev + (size_t)lyr * HB, k0, b4, acc);

            // reduce the wave's 4 k-subchunks (lanes xor 16, 32)
#pragma unroll
            for (int r = 0; r < 8; ++r) {
                float4 a = acc[r];
                a.x += __shfl_xor(a.x, 16); a.y += __shfl_xor(a.y, 16);
                a.z += __shfl_xor(a.z, 16); a.w += __shfl_xor(a.w, 16);
                a.x += __shfl_xor(a.x, 32); a.y += __shfl_xor(a.y, 32);
                a.z += __shfl_xor(a.z, 32); a.w += __shfl_xor(a.w, 32);
                acc[r] = a;
            }
            if ((tid & 48) == 0) {
#pragma unroll
                for (int r = 0; r < 8; ++r)
                    *(float4*)&sm[OFF_PART + (wv_ * 8 + r) * Bsz + b4] = acc[r];
            }
            __syncthreads();

            // stage A: one gate value per thread
            {
                const int r = tid >> 6, b = tid & 63;
                float v = sm[OFF_BS + lyr * 8 + r];
#pragma unroll
                for (int q = 0; q < 8; ++q)
                    v += sm[OFF_PART + (q * 8 + r) * Bsz + b];
                if (lyr == 0) {
                    const float xv = fut ? sm[OFF_XS + b] : iput[b * Tn + t];
                    v = fmaf(xv, sm[OFF_W0 + r], v);
                }
                sm[OFF_GSUM + tid] = v;
            }
            __syncthreads();

            // stage B: LSTM elementwise update
            float h2 = 0.0f;
            if (tid < 128) {
                const int jl = tid >> 6, b = tid & 63;
                const int jg = bi * 2 + jl;
                const float* gs = sm + OFF_GSUM + jl * 4 * Bsz;
                const float i_ = sigm(gs[0 * Bsz + b]);
                const float f_ = sigm(gs[1 * Bsz + b]);
                const float g_ = tanhf(gs[2 * Bsz + b]);
                const float o_ = sigm(gs[3 * Bsz + b]);
                float* cp = sm + OFF_C + (lyr * 2 + jl) * Bsz + b;
                const float c2 = fmaf(f_, *cp, i_ * g_);
                *cp = c2;
                h2 = o_ * tanhf(c2);
                st_agent(&hcur[((size_t)lyr * Hn + jg) * Bsz + b], h2);
                if (lyr == 3) {
                    if (!fut)
                        st_agent(&g_hist[((size_t)t * Hn + jg) * Bsz + b], h2);
                    else if (jl == 1)
                        sm[OFF_RP + b] = h2 * sm[OFF_WLIN + jg];
                }
            }
            __syncthreads();
            if (fut && lyr == 3 && tid < Bsz) {
                const float pv = fmaf(h2, sm[OFF_WLIN + bi * 2], sm[OFF_RP + tid]);
                st_agent(&g_p[tid * NBLK + bi], pv);
            }
            gbar(bi, tid, sense);
        }

        // ---- after warmup: batched readout of out[:,0..255]; block t'=bi
        if (t == Tn - 1) {
            const int b = tid & 63, jq = tid >> 6;
            const float* hp = g_hist + ((size_t)bi * Hn + jq * 64) * Bsz + b;
            const float* wp = sm + OFF_WLIN + jq * 64;
            float r = 0.0f;
#pragma unroll 8
            for (int j = 0; j < 64; ++j) r = fmaf(hp[j * Bsz], wp[j], r);
            sm[OFF_RP + jq * Bsz + b] = r;
            __syncthreads();
            if (tid < Bsz) {
                float x = blin0;
#pragma unroll
                for (int q = 0; q < 8; ++q) x += sm[OFF_RP + q * Bsz + tid];
                st_agent(&out[tid * TTn + bi], x);
                if (bi == 255) st_agent(&g_xsg[tid], x);
            }
            gbar(bi, tid, sense);
        }
    }

    // ---- final readout out[:,319] from p of t=319
    if (bi == 0 && tid < Bsz) {
        const float4* pp = (const float4*)(g_p + tid * NBLK);
        float4 s4 = make_float4(0.f, 0.f, 0.f, 0.f);
#pragma unroll 16
        for (int q = 0; q < NBLK / 4; ++q) {
            const float4 v = pp[q];
            s4.x += v.x; s4.y += v.y; s4.z += v.z; s4.w += v.w;
        }
        st_agent(&out[tid * TTn + (TTn - 1)], s4.x + s4.y + s4.z + s4.w + blin0);
    }
}

extern "C" void kernel_launch(void* const* d_in, const int* in_sizes, int n_in,
                              void* d_out, int out_size, void* d_ws, size_t ws_size,
                              hipStream_t stream) {
    const float* iput = (const float*)d_in[0];
    const float* Wih0 = (const float*)d_in[1];
    const float* Wih  = (const float*)d_in[2];
    const float* Whh  = (const float*)d_in[3];
    const float* bih  = (const float*)d_in[4];
    const float* bhh  = (const float*)d_in[5];
    const float* Wlin = (const float*)d_in[6];
    const float* blin = (const float*)d_in[7];
    float* out = (float*)d_out;

    (void)hipFuncSetAttribute((const void*)lstm_seq,
                              hipFuncAttributeMaxDynamicSharedMemorySize, SMEM_BYTES);

    void* args[] = {&iput, &Wih0, &Wih, &Whh, &bih, &bhh, &Wlin, &blin, &out};
    hipLaunchCooperativeKernel((const void*)lstm_seq, dim3(NBLK), dim3(NTHR), args,
                               SMEM_BYTES, stream);
}

// Round 8
// 12689.010 us; speedup vs baseline: 5.3253x; 1.2476x over previous
//
#include <hip/hip_runtime.h>

#define Bsz 64
#define Tn 256
#define Hn 512
#define Ln 4
#define Gn 2048
#define TTn 320
#define NBLK 256
#define NTHR 512
#define HB (Hn * Bsz)
#define LHB (Ln * HB)
#define NPH_W (Tn + Ln - 1)   // 259 diagonal warmup phases

typedef float f32x4 __attribute__((ext_vector_type(4)));

// ---- LDS layout (float offsets) ----
#define OFF_WHH  0                                // [4][8][512]
#define OFF_WIH  (OFF_WHH + Ln * 8 * Hn)          // [3][8][512]
#define OFF_PART (OFF_WIH + (Ln - 1) * 8 * Hn)    // warmup [4][2][8][64] / future [8][8][64]
#define OFF_GSUM (OFF_PART + 8 * 8 * Bsz)         // warmup [4][8][64] / future [8][64]
#define OFF_BS   (OFF_GSUM + Ln * 8 * Bsz)        // [4][8]
#define OFF_W0   (OFF_BS + Ln * 8)                // [8]
#define OFF_WLIN (OFF_W0 + 8)                     // [512]
#define OFF_RP   (OFF_WLIN + Hn)                  // [8][64]
#define OFF_XS   (OFF_RP + 8 * Bsz)               // [64]
#define OFF_C    (OFF_XS + Bsz)                   // [4][2][64]
#define SMEM_FLOATS (OFF_C + Ln * 2 * Bsz)
#define SMEM_BYTES (SMEM_FLOATS * 4)              // ~142.4 KB

// ---- workspace (u32; zeroed by hipMemsetAsync each launch) ----
#define WS_ARRIVE 0                    // [8][32] spaced arrival counters
#define WS_MASTER 256
#define WS_FLAG   288
#define WS_U32S   320

__device__ float g_h[2 * LHB];        // h double-buffered by phase/t parity
__device__ float g_hist[Tn * HB];     // h3 history for batched warmup readout
__device__ float g_p[Bsz * NBLK];     // distributed readout partials [b][block]
__device__ float g_xsg[Bsz];          // x seed for t=256

__device__ __forceinline__ float sigm(float x) { return 1.0f / (1.0f + expf(-x)); }

__device__ __forceinline__ void fma4v(f32x4& a, const f32x4 h, const float w) {
    a.x = fmaf(h.x, w, a.x); a.y = fmaf(h.y, w, a.y);
    a.z = fmaf(h.z, w, a.z); a.w = fmaf(h.w, w, a.w);
}

__device__ __forceinline__ uint32_t rmw_add(uint32_t* p, uint32_t v) {
    return __hip_atomic_fetch_add(p, v, __ATOMIC_RELAXED, __HIP_MEMORY_SCOPE_AGENT);
}
__device__ __forceinline__ uint32_t ald(const uint32_t* p) {
    return __hip_atomic_load(p, __ATOMIC_RELAXED, __HIP_MEMORY_SCOPE_AGENT);
}

// R3-proven barrier: per-block release (wbl2) before arrive, per-block acquire
// (inv: L1+L2) after the gate opens. Monotonic epoch counters in d_ws
// (memset-zeroed each launch -> graph-replay safe).
__device__ __forceinline__ void gbar(uint32_t* wsb, int bi, int tid, uint32_t& e) {
    ++e;
    __syncthreads();   // compiler drains vmcnt before s_barrier
    if (tid == 0) {
        __builtin_amdgcn_fence(__ATOMIC_RELEASE, "agent");   // flush L2 -> L3
        uint32_t old = rmw_add(wsb + WS_ARRIVE + (bi & 7) * 32, 1u);
        if (old == e * 32u - 1u) {              // last arrival of this group
            uint32_t m = rmw_add(wsb + WS_MASTER, 1u);
            if (m == e * 8u - 1u)               // last group
                rmw_add(wsb + WS_FLAG, 1u);
        }
        while (ald(wsb + WS_FLAG) < e) __builtin_amdgcn_s_sleep(1);
        __builtin_amdgcn_fence(__ATOMIC_ACQUIRE, "agent");   // inv L1+L2
    }
    __syncthreads();
    asm volatile("" ::: "memory");
}

// Future-section partial GEMM (R3-proven): thread's 16-k chunk, plain loads.
__device__ __forceinline__ void gemm16(const float* __restrict__ w,     // LDS [8][512]
                                       const float* __restrict__ hbase, // global [512][64]
                                       int k0, int b4, f32x4* acc) {
#pragma unroll
    for (int c = 0; c < 4; ++c) {
        const int k = k0 + c * 4;
        const float* hp = hbase + (size_t)k * Bsz + b4;
        const f32x4 h0 = *(const f32x4*)(hp);
        const f32x4 h1 = *(const f32x4*)(hp + Bsz);
        const f32x4 h2 = *(const f32x4*)(hp + 2 * Bsz);
        const f32x4 h3 = *(const f32x4*)(hp + 3 * Bsz);
#pragma unroll
        for (int r = 0; r < 8; ++r) {
            const f32x4 wv = *(const f32x4*)(w + r * Hn + k);
            fma4v(acc[r], h0, wv.x); fma4v(acc[r], h1, wv.y);
            fma4v(acc[r], h2, wv.z); fma4v(acc[r], h3, wv.w);
        }
    }
}

__global__ __launch_bounds__(NTHR, 1)
void lstm_seq(const float* __restrict__ iput,   // [B][T]
              const float* __restrict__ Wih0,   // [2048]
              const float* __restrict__ Wih,    // [3][2048][512]
              const float* __restrict__ Whh,    // [4][2048][512]
              const float* __restrict__ bih,    // [4][2048]
              const float* __restrict__ bhh,    // [4][2048]
              const float* __restrict__ Wlin,   // [512]
              const float* __restrict__ blin,   // [1]
              float* __restrict__ out,          // [B][320]
              uint32_t* __restrict__ wsb)       // barrier state (zeroed)
{
    extern __shared__ float sm[];
    const int bi  = blockIdx.x;
    const int tid = threadIdx.x;
    uint32_t e = 0;

    // ---- stage weights into LDS (row r=(jl<<2)|q -> gate row q*512+bi*2+jl)
    for (int i = tid; i < Ln * 8 * Hn; i += NTHR) {
        const int lyr = i >> 12, rem = i & 4095, r = rem >> 9, k = rem & 511;
        sm[OFF_WHH + i] = Whh[((size_t)(lyr * Gn + (r & 3) * Hn + bi * 2 + (r >> 2))) * Hn + k];
    }
    for (int i = tid; i < (Ln - 1) * 8 * Hn; i += NTHR) {
        const int lyr = i >> 12, rem = i & 4095, r = rem >> 9, k = rem & 511;
        sm[OFF_WIH + i] = Wih[((size_t)(lyr * Gn + (r & 3) * Hn + bi * 2 + (r >> 2))) * Hn + k];
    }
    if (tid < Ln * 8) {
        const int lyr = tid >> 3, r = tid & 7;
        const int gg = lyr * Gn + (r & 3) * Hn + bi * 2 + (r >> 2);
        sm[OFF_BS + tid] = bih[gg] + bhh[gg];
    }
    if (tid < 8) sm[OFF_W0 + tid] = Wih0[(tid & 3) * Hn + bi * 2 + (tid >> 2)];
    for (int i = tid; i < Hn; i += NTHR) sm[OFF_WLIN + i] = Wlin[i];
    for (int i = tid; i < Ln * 2 * Bsz; i += NTHR) sm[OFF_C + i] = 0.0f;

    // zero persistent h (both parities; gbar's release flushes)
    for (int i = bi * NTHR + tid; i < 2 * LHB; i += NBLK * NTHR) g_h[i] = 0.0f;

    const float blin0 = blin[0];
    gbar(wsb, bi, tid, e);

    // ============ warmup: diagonal wavefront, 1 barrier per phase ============
    // phase s: layer l computes t = s - l (active iff 0 <= t < 256).
    // All reads are phase-(s-1) outputs -> double-buffer by phase parity.
    {
        const int l   = tid >> 7;        // this thread's layer 0..3
        const int sub = tid & 127;
        const int bgw = sub & 15, b4w = bgw * 4;
        const int kgw = sub >> 4;        // 0..7, k-chunk of 64
        const int k0w = kgw * 64;
        const int w2  = (tid >> 6) & 1;  // wave-within-layer

        for (int s = 0; s < NPH_W; ++s) {
            const int pp = s & 1;
            float* cur        = g_h + pp * LHB;
            const float* prev = g_h + (pp ^ 1) * LHB;
            const int t = s - l;
            const bool act = ((unsigned)t < (unsigned)Tn);

            f32x4 acc[8];
#pragma unroll
            for (int r = 0; r < 8; ++r) acc[r] = (f32x4){0.f, 0.f, 0.f, 0.f};

            if (act) {
                {   // hidden-hidden: h_l(t-1) = prev[l]
                    const float* wh  = sm + OFF_WHH + l * 8 * Hn;
                    const float* hp0 = prev + (size_t)l * HB;
#pragma unroll 4
                    for (int c = 0; c < 16; ++c) {
                        const int k = k0w + (((c + (kgw & 3) * 4) & 15) << 2);
                        const float* hp = hp0 + (size_t)k * Bsz + b4w;
                        const f32x4 h0 = *(const f32x4*)(hp);
                        const f32x4 h1 = *(const f32x4*)(hp + Bsz);
                        const f32x4 h2 = *(const f32x4*)(hp + 2 * Bsz);
                        const f32x4 h3 = *(const f32x4*)(hp + 3 * Bsz);
#pragma unroll
                        for (int r = 0; r < 8; ++r) {
                            const f32x4 wv = *(const f32x4*)(wh + r * Hn + k);
                            fma4v(acc[r], h0, wv.x); fma4v(acc[r], h1, wv.y);
                            fma4v(acc[r], h2, wv.z); fma4v(acc[r], h3, wv.w);
                        }
                    }
                }
                if (l > 0) {   // input: h_{l-1}(t) = prev[l-1]
                    const float* wh  = sm + OFF_WIH + (l - 1) * 8 * Hn;
                    const float* hp0 = prev + (size_t)(l - 1) * HB;
#pragma unroll 4
                    for (int c = 0; c < 16; ++c) {
                        const int k = k0w + (((c + (kgw & 3) * 4) & 15) << 2);
                        const float* hp = hp0 + (size_t)k * Bsz + b4w;
                        const f32x4 h0 = *(const f32x4*)(hp);
                        const f32x4 h1 = *(const f32x4*)(hp + Bsz);
                        const f32x4 h2 = *(const f32x4*)(hp + 2 * Bsz);
                        const f32x4 h3 = *(const f32x4*)(hp + 3 * Bsz);
#pragma unroll
                        for (int r = 0; r < 8; ++r) {
                            const f32x4 wv = *(const f32x4*)(wh + r * Hn + k);
                            fma4v(acc[r], h0, wv.x); fma4v(acc[r], h1, wv.y);
                            fma4v(acc[r], h2, wv.z); fma4v(acc[r], h3, wv.w);
                        }
                    }
                }
            }

            // in-wave reduce over the wave's 4 kg-chunks (lanes xor 16, 32)
#pragma unroll
            for (int r = 0; r < 8; ++r) {
                f32x4 a = acc[r];
                a.x += __shfl_xor(a.x, 16); a.y += __shfl_xor(a.y, 16);
                a.z += __shfl_xor(a.z, 16); a.w += __shfl_xor(a.w, 16);
                a.x += __shfl_xor(a.x, 32); a.y += __shfl_xor(a.y, 32);
                a.z += __shfl_xor(a.z, 32); a.w += __shfl_xor(a.w, 32);
                acc[r] = a;
            }
            if ((tid & 48) == 0) {
#pragma unroll
                for (int r = 0; r < 8; ++r)
                    *(f32x4*)&sm[OFF_PART + ((l * 2 + w2) * 8 + r) * Bsz + b4w] = acc[r];
            }
            __syncthreads();

            // stage A: 2048 gate values (4 per thread)
#pragma unroll
            for (int it = 0; it < 4; ++it) {
                const int idx = it * NTHR + tid;
                const int la = idx >> 9, r = (idx >> 6) & 7, b = idx & 63;
                float v = sm[OFF_BS + la * 8 + r]
                        + sm[OFF_PART + ((la * 2 + 0) * 8 + r) * Bsz + b]
                        + sm[OFF_PART + ((la * 2 + 1) * 8 + r) * Bsz + b];
                if (la == 0 && s < Tn)
                    v = fmaf(iput[b * Tn + s], sm[OFF_W0 + r], v);
                sm[OFF_GSUM + idx] = v;
            }
            __syncthreads();

            // stage B: one cell element per thread (4 layers x 2 cols x 64 b)
            {
                const int lb = tid >> 7, jl = (tid >> 6) & 1, b = tid & 63;
                const int tb = s - lb;
                if ((unsigned)tb < (unsigned)Tn) {
                    const int jg = bi * 2 + jl;
                    const float* gs = sm + OFF_GSUM + lb * 512 + (jl << 2) * 64;
                    const float i_ = sigm(gs[0 * 64 + b]);
                    const float f_ = sigm(gs[1 * 64 + b]);
                    const float g_ = tanhf(gs[2 * 64 + b]);
                    const float o_ = sigm(gs[3 * 64 + b]);
                    float* cp = sm + OFF_C + (lb * 2 + jl) * Bsz + b;
                    const float c2 = fmaf(f_, *cp, i_ * g_);
                    *cp = c2;
                    const float h2 = o_ * tanhf(c2);
                    cur[((size_t)lb * Hn + jg) * Bsz + b] = h2;
                    if (lb == 3)
                        g_hist[((size_t)tb * Hn + jg) * Bsz + b] = h2;
                }
            }
            gbar(wsb, bi, tid, e);
        }
    }

    // ============ batched readout of out[:,0..255] + parity consolidation ====
    {
        const int b = tid & 63, jq = tid >> 6;
        const float* hp = g_hist + ((size_t)bi * Hn + jq * 64) * Bsz + b;
        const float* wp = sm + OFF_WLIN + jq * 64;
        float r = 0.0f;
#pragma unroll 8
        for (int j = 0; j < 64; ++j) r = fmaf(hp[j * Bsz], wp[j], r);
        sm[OFF_RP + jq * Bsz + b] = r;
        // copy h_l(255) for l=1,3 from parity-0 buffer into parity-1 buffer
        // (own columns only; l=0,2 already live in parity 1)
        if (tid < 256) {
            const int li = (tid >> 7) * 2 + 1;          // 1 or 3
            const int jl = (tid >> 6) & 1, bb = tid & 63;
            const size_t o = ((size_t)li * Hn + bi * 2 + jl) * Bsz + bb;
            g_h[LHB + o] = g_h[o];
        }
        __syncthreads();
        if (tid < Bsz) {
            float x = blin0;
#pragma unroll
            for (int q = 0; q < 8; ++q) x += sm[OFF_RP + q * Bsz + tid];
            out[tid * TTn + bi] = x;
            if (bi == 255) g_xsg[tid] = x;
        }
        gbar(wsb, bi, tid, e);
    }

    // ============ future phase: serial 4-layer chain + folded readout =======
    {
        const int bg  = tid & 15, b4 = bg * 4;
        const int kg  = tid >> 4;        // 0..31, chunk of 16 k
        const int k0  = kg * 16;
        const int wv_ = tid >> 6;

        for (int t = Tn; t < TTn; ++t) {
            const int ci = t & 1;
            float* hcur        = g_h + ci * LHB;
            const float* hprev = g_h + (ci ^ 1) * LHB;

            for (int lyr = 0; lyr < Ln; ++lyr) {
                // x for this t: wave 0 sums distributed partials (overlaps GEMM)
                if (lyr == 0 && tid < Bsz) {
                    float x;
                    if (t == Tn) {
                        x = g_xsg[tid];
                    } else {
                        const f32x4* pp2 = (const f32x4*)(g_p + tid * NBLK);
                        f32x4 s4 = {0.f, 0.f, 0.f, 0.f};
#pragma unroll 16
                        for (int q = 0; q < NBLK / 4; ++q) s4 += pp2[q];
                        x = s4.x + s4.y + s4.z + s4.w + blin0;
                        if (bi == ((t - 1) & 255))
                            out[tid * TTn + (t - 1)] = x;
                    }
                    sm[OFF_XS + tid] = x;
                }

                f32x4 acc[8];
#pragma unroll
                for (int r = 0; r < 8; ++r) acc[r] = (f32x4){0.f, 0.f, 0.f, 0.f};

                if (lyr > 0)
                    gemm16(sm + OFF_WIH + (lyr - 1) * 8 * Hn,
                           hcur + (size_t)(lyr - 1) * HB, k0, b4, acc);
                gemm16(sm + OFF_WHH + lyr * 8 * Hn,
                       hprev + (size_t)lyr * HB, k0, b4, acc);

#pragma unroll
                for (int r = 0; r < 8; ++r) {
                    f32x4 a = acc[r];
                    a.x += __shfl_xor(a.x, 16); a.y += __shfl_xor(a.y, 16);
                    a.z += __shfl_xor(a.z, 16); a.w += __shfl_xor(a.w, 16);
                    a.x += __shfl_xor(a.x, 32); a.y += __shfl_xor(a.y, 32);
                    a.z += __shfl_xor(a.z, 32); a.w += __shfl_xor(a.w, 32);
                    acc[r] = a;
                }
                if ((tid & 48) == 0) {
#pragma unroll
                    for (int r = 0; r < 8; ++r)
                        *(f32x4*)&sm[OFF_PART + (wv_ * 8 + r) * Bsz + b4] = acc[r];
                }
                __syncthreads();

                {   // stage A: one gate value per thread
                    const int r = tid >> 6, b = tid & 63;
                    float v = sm[OFF_BS + lyr * 8 + r];
#pragma unroll
                    for (int q = 0; q < 8; ++q)
                        v += sm[OFF_PART + (q * 8 + r) * Bsz + b];
                    if (lyr == 0)
                        v = fmaf(sm[OFF_XS + b], sm[OFF_W0 + r], v);
                    sm[OFF_GSUM + tid] = v;
                }
                __syncthreads();

                // stage B
                float h2 = 0.0f;
                if (tid < 128) {
                    const int jl = tid >> 6, b = tid & 63;
                    const int jg = bi * 2 + jl;
                    const float* gs = sm + OFF_GSUM + jl * 4 * Bsz;
                    const float i_ = sigm(gs[0 * Bsz + b]);
                    const float f_ = sigm(gs[1 * Bsz + b]);
                    const float g_ = tanhf(gs[2 * Bsz + b]);
                    const float o_ = sigm(gs[3 * Bsz + b]);
                    float* cp = sm + OFF_C + (lyr * 2 + jl) * Bsz + b;
                    const float c2 = fmaf(f_, *cp, i_ * g_);
                    *cp = c2;
                    h2 = o_ * tanhf(c2);
                    hcur[((size_t)lyr * Hn + jg) * Bsz + b] = h2;
                    if (lyr == 3 && jl == 1)
                        sm[OFF_RP + b] = h2 * sm[OFF_WLIN + jg];
                }
                __syncthreads();
                if (lyr == 3 && tid < Bsz)
                    g_p[tid * NBLK + bi] = fmaf(h2, sm[OFF_WLIN + bi * 2], sm[OFF_RP + tid]);

                gbar(wsb, bi, tid, e);
            }
        }
    }

    // ---- final readout out[:,319]
    if (bi == 0 && tid < Bsz) {
        const f32x4* pp2 = (const f32x4*)(g_p + tid * NBLK);
        f32x4 s4 = {0.f, 0.f, 0.f, 0.f};
#pragma unroll 16
        for (int q = 0; q < NBLK / 4; ++q) s4 += pp2[q];
        out[tid * TTn + (TTn - 1)] = s4.x + s4.y + s4.z + s4.w + blin0;
    }
}

extern "C" void kernel_launch(void* const* d_in, const int* in_sizes, int n_in,
                              void* d_out, int out_size, void* d_ws, size_t ws_size,
                              hipStream_t stream) {
    const float* iput = (const float*)d_in[0];
    const float* Wih0 = (const float*)d_in[1];
    const float* Wih  = (const float*)d_in[2];
    const float* Whh  = (const float*)d_in[3];
    const float* bih  = (const float*)d_in[4];
    const float* bhh  = (const float*)d_in[5];
    const float* Wlin = (const float*)d_in[6];
    const float* blin = (const float*)d_in[7];
    float* out = (float*)d_out;
    uint32_t* wsb = (uint32_t*)d_ws;

    (void)hipFuncSetAttribute((const void*)lstm_seq,
                              hipFuncAttributeMaxDynamicSharedMemorySize, SMEM_BYTES);

    // zero barrier state each launch (graph-capturable async memset)
    (void)hipMemsetAsync(d_ws, 0, WS_U32S * sizeof(uint32_t), stream);

    void* args[] = {&iput, &Wih0, &Wih, &Whh, &bih, &bhh, &Wlin, &blin, &out, &wsb};
    hipLaunchCooperativeKernel((const void*)lstm_seq, dim3(NBLK), dim3(NTHR), args,
                               SMEM_BYTES, stream);
}

// Round 9
// 9710.248 us; speedup vs baseline: 6.9589x; 1.3068x over previous
//
#include <hip/hip_runtime.h>

#define Bsz 64
#define Tn 256
#define Hn 512
#define Ln 4
#define Gn 2048
#define TTn 320
#define NBLK 256
#define NTHR 512
#define HB (Hn * Bsz)
#define LHB (Ln * HB)
#define NPH_W (Tn + Ln - 1)   // 259 diagonal warmup phases

typedef float f32x4 __attribute__((ext_vector_type(4)));

// ---- LDS layout (float offsets) ----
#define OFF_WHH  0                                // [4][8][512]
#define OFF_WIH  (OFF_WHH + Ln * 8 * Hn)          // [3][8][512]
#define OFF_PART (OFF_WIH + (Ln - 1) * 8 * Hn)    // warmup [4][2][8][64] / future [8][8][64]
#define OFF_GSUM (OFF_PART + 8 * 8 * Bsz)         // warmup [4][8][64] / future [8][64]
#define OFF_BS   (OFF_GSUM + Ln * 8 * Bsz)        // [4][8]
#define OFF_W0   (OFF_BS + Ln * 8)                // [8]
#define OFF_WLIN (OFF_W0 + 8)                     // [512]
#define OFF_RP   (OFF_WLIN + Hn)                  // [8][64]
#define OFF_XS   (OFF_RP + 8 * Bsz)               // [64]
#define OFF_C    (OFF_XS + Bsz)                   // [4][2][64]
#define SMEM_FLOATS (OFF_C + Ln * 2 * Bsz)
#define SMEM_BYTES (SMEM_FLOATS * 4)              // ~142.4 KB

// ---- workspace (u32; zeroed by hipMemsetAsync each launch) ----
#define WS_BCOUNT   0                    // [16] blocks per XCD (discovery)
#define WS_ARRIVE   16                   // [16][32] per-XCD arrival ctrs (spaced)
#define WS_MASTER   (16 + 16 * 32)
#define WS_FLAG     (WS_MASTER + 32)
#define WS_BOOT     (WS_FLAG + 32)
#define WS_BOOTFLAG (WS_BOOT + 32)
#define WS_U32S     (WS_BOOTFLAG + 32)

__device__ float g_h[2 * LHB];        // h double-buffered by phase/t parity
__device__ float g_hist[Tn * HB];     // h3 history for batched warmup readout
__device__ float g_p[Bsz * NBLK];     // distributed readout partials [b][block]
__device__ float g_xsg[Bsz];          // x seed for t=256

__device__ __forceinline__ float sigm(float x) { return 1.0f / (1.0f + expf(-x)); }

__device__ __forceinline__ void fma4v(f32x4& a, const f32x4 h, const float w) {
    a.x = fmaf(h.x, w, a.x); a.y = fmaf(h.y, w, a.y);
    a.z = fmaf(h.z, w, a.z); a.w = fmaf(h.w, w, a.w);
}

// write-through store toward the L3 coherence point. Correct under either
// semantics: if it writes through, the leader's wbl2 is near-empty (fast);
// if it only reaches L2, the leader's wbl2 still flushes it (R3-proven).
#define GSTF(ptr, val) \
    asm volatile("global_store_dword %0, %1, off sc0 sc1" \
                 :: "v"(ptr), "v"(val) : "memory")
#define VMWAIT() asm volatile("s_waitcnt vmcnt(0)" ::: "memory")

__device__ __forceinline__ uint32_t rmw_add(uint32_t* p, uint32_t v) {
    return __hip_atomic_fetch_add(p, v, __ATOMIC_RELAXED, __HIP_MEMORY_SCOPE_AGENT);
}
__device__ __forceinline__ uint32_t ald(const uint32_t* p) {
    return __hip_atomic_load(p, __ATOMIC_RELAXED, __HIP_MEMORY_SCOPE_AGENT);
}
__device__ __forceinline__ uint32_t xcc_id() {
    uint32_t x;
    asm("s_getreg_b32 %0, hwreg(HW_REG_XCC_ID)" : "=s"(x));
    return x & 15u;
}

// Bootstrap barrier (once): per-block release+acquire, counts blocks per XCD.
__device__ __forceinline__ void boot_bar(uint32_t* wsb, int tid) {
    VMWAIT();
    __syncthreads();
    if (tid == 0) {
        __builtin_amdgcn_fence(__ATOMIC_RELEASE, "agent");
        uint32_t old = rmw_add(wsb + WS_BOOT, 1u);
        if (old == NBLK - 1u) rmw_add(wsb + WS_BOOTFLAG, 1u);
        while (ald(wsb + WS_BOOTFLAG) < 1u) __builtin_amdgcn_s_sleep(2);
        __builtin_amdgcn_fence(__ATOMIC_ACQUIRE, "agent");
    }
    __syncthreads();
    asm volatile("" ::: "memory");
}

// Fast grid barrier: leader-only RELEASE (one wbl2 per XCD, executed by the
// last arriver of that XCD after all its peers' stores are in the shared L2),
// per-block ACQUIRE (L1+L2 inv — the piece R5-R7 proved non-negotiable).
__device__ __forceinline__ void gbar(uint32_t* wsb, int tid, uint32_t x,
                                     uint32_t cnt_x, uint32_t& e) {
    ++e;
    VMWAIT();          // drain asm stores (to L2-or-L3) before arriving
    __syncthreads();
    if (tid == 0) {
        uint32_t old = rmw_add(wsb + WS_ARRIVE + x * 32, 1u);
        if (old == e * cnt_x - 1u) {            // last arriver on this XCD
            __builtin_amdgcn_fence(__ATOMIC_RELEASE, "agent");  // one wbl2/XCD
            uint32_t m = rmw_add(wsb + WS_MASTER, cnt_x);
            if (m + cnt_x == e * (uint32_t)NBLK)
                rmw_add(wsb + WS_FLAG, 1u);     // last XCD: open the gate
        }
        while (ald(wsb + WS_FLAG) < e) __builtin_amdgcn_s_sleep(2);
        __builtin_amdgcn_fence(__ATOMIC_ACQUIRE, "agent");      // inv L1+L2
    }
    __syncthreads();
    asm volatile("" ::: "memory");
}

// Future-section partial GEMM: thread's 16-k chunk, plain loads.
__device__ __forceinline__ void gemm16(const float* __restrict__ w,     // LDS [8][512]
                                       const float* __restrict__ hbase, // global [512][64]
                                       int k0, int b4, f32x4* acc) {
#pragma unroll
    for (int c = 0; c < 4; ++c) {
        const int k = k0 + c * 4;
        const float* hp = hbase + (size_t)k * Bsz + b4;
        const f32x4 h0 = *(const f32x4*)(hp);
        const f32x4 h1 = *(const f32x4*)(hp + Bsz);
        const f32x4 h2 = *(const f32x4*)(hp + 2 * Bsz);
        const f32x4 h3 = *(const f32x4*)(hp + 3 * Bsz);
#pragma unroll
        for (int r = 0; r < 8; ++r) {
            const f32x4 wv = *(const f32x4*)(w + r * Hn + k);
            fma4v(acc[r], h0, wv.x); fma4v(acc[r], h1, wv.y);
            fma4v(acc[r], h2, wv.z); fma4v(acc[r], h3, wv.w);
        }
    }
}

__global__ __launch_bounds__(NTHR, 1)
void lstm_seq(const float* __restrict__ iput,   // [B][T]
              const float* __restrict__ Wih0,   // [2048]
              const float* __restrict__ Wih,    // [3][2048][512]
              const float* __restrict__ Whh,    // [4][2048][512]
              const float* __restrict__ bih,    // [4][2048]
              const float* __restrict__ bhh,    // [4][2048]
              const float* __restrict__ Wlin,   // [512]
              const float* __restrict__ blin,   // [1]
              float* __restrict__ out,          // [B][320]
              uint32_t* __restrict__ wsb)       // barrier state (zeroed)
{
    extern __shared__ float sm[];
    const int bi  = blockIdx.x;
    const int tid = threadIdx.x;
    uint32_t e = 0;

    const uint32_t x = xcc_id();
    uint32_t cnt_x = 0;
    if (tid == 0) rmw_add(wsb + WS_BCOUNT + x, 1u);   // discovery

    // ---- stage weights into LDS (row r=(jl<<2)|q -> gate row q*512+bi*2+jl)
    for (int i = tid; i < Ln * 8 * Hn; i += NTHR) {
        const int lyr = i >> 12, rem = i & 4095, r = rem >> 9, k = rem & 511;
        sm[OFF_WHH + i] = Whh[((size_t)(lyr * Gn + (r & 3) * Hn + bi * 2 + (r >> 2))) * Hn + k];
    }
    for (int i = tid; i < (Ln - 1) * 8 * Hn; i += NTHR) {
        const int lyr = i >> 12, rem = i & 4095, r = rem >> 9, k = rem & 511;
        sm[OFF_WIH + i] = Wih[((size_t)(lyr * Gn + (r & 3) * Hn + bi * 2 + (r >> 2))) * Hn + k];
    }
    if (tid < Ln * 8) {
        const int lyr = tid >> 3, r = tid & 7;
        const int gg = lyr * Gn + (r & 3) * Hn + bi * 2 + (r >> 2);
        sm[OFF_BS + tid] = bih[gg] + bhh[gg];
    }
    if (tid < 8) sm[OFF_W0 + tid] = Wih0[(tid & 3) * Hn + bi * 2 + (tid >> 2)];
    for (int i = tid; i < Hn; i += NTHR) sm[OFF_WLIN + i] = Wlin[i];
    for (int i = tid; i < Ln * 2 * Bsz; i += NTHR) sm[OFF_C + i] = 0.0f;

    // zero persistent h (write-through; boot_bar release covers either way)
    for (int i = bi * NTHR + tid; i < 2 * LHB; i += NBLK * NTHR)
        GSTF(&g_h[i], 0.0f);

    const float blin0 = blin[0];
    boot_bar(wsb, tid);
    if (tid == 0) cnt_x = ald(wsb + WS_BCOUNT + x);   // final per-XCD count

    // ============ warmup: diagonal wavefront, 1 barrier per phase ============
    // phase s: layer l computes t = s - l (active iff 0 <= t < 256).
    {
        const int l   = tid >> 7;        // this thread's layer 0..3
        const int sub = tid & 127;
        const int bgw = sub & 15, b4w = bgw * 4;
        const int kgw = sub >> 4;        // 0..7, k-chunk of 64
        const int k0w = kgw * 64;
        const int w2  = (tid >> 6) & 1;  // wave-within-layer

        for (int s = 0; s < NPH_W; ++s) {
            const int pp = s & 1;
            float* cur        = g_h + pp * LHB;
            const float* prev = g_h + (pp ^ 1) * LHB;
            const int t = s - l;
            const bool act = ((unsigned)t < (unsigned)Tn);

            f32x4 acc[8];
#pragma unroll
            for (int r = 0; r < 8; ++r) acc[r] = (f32x4){0.f, 0.f, 0.f, 0.f};

            if (act) {
                {   // hidden-hidden: h_l(t-1) = prev[l]
                    const float* wh  = sm + OFF_WHH + l * 8 * Hn;
                    const float* hp0 = prev + (size_t)l * HB;
#pragma unroll 4
                    for (int c = 0; c < 16; ++c) {
                        const int k = k0w + (((c + (kgw & 3) * 4) & 15) << 2);
                        const float* hp = hp0 + (size_t)k * Bsz + b4w;
                        const f32x4 h0 = *(const f32x4*)(hp);
                        const f32x4 h1 = *(const f32x4*)(hp + Bsz);
                        const f32x4 h2 = *(const f32x4*)(hp + 2 * Bsz);
                        const f32x4 h3 = *(const f32x4*)(hp + 3 * Bsz);
#pragma unroll
                        for (int r = 0; r < 8; ++r) {
                            const f32x4 wv = *(const f32x4*)(wh + r * Hn + k);
                            fma4v(acc[r], h0, wv.x); fma4v(acc[r], h1, wv.y);
                            fma4v(acc[r], h2, wv.z); fma4v(acc[r], h3, wv.w);
                        }
                    }
                }
                if (l > 0) {   // input: h_{l-1}(t) = prev[l-1]
                    const float* wh  = sm + OFF_WIH + (l - 1) * 8 * Hn;
                    const float* hp0 = prev + (size_t)(l - 1) * HB;
#pragma unroll 4
                    for (int c = 0; c < 16; ++c) {
                        const int k = k0w + (((c + (kgw & 3) * 4) & 15) << 2);
                        const float* hp = hp0 + (size_t)k * Bsz + b4w;
                        const f32x4 h0 = *(const f32x4*)(hp);
                        const f32x4 h1 = *(const f32x4*)(hp + Bsz);
                        const f32x4 h2 = *(const f32x4*)(hp + 2 * Bsz);
                        const f32x4 h3 = *(const f32x4*)(hp + 3 * Bsz);
#pragma unroll
                        for (int r = 0; r < 8; ++r) {
                            const f32x4 wv = *(const f32x4*)(wh + r * Hn + k);
                            fma4v(acc[r], h0, wv.x); fma4v(acc[r], h1, wv.y);
                            fma4v(acc[r], h2, wv.z); fma4v(acc[r], h3, wv.w);
                        }
                    }
                }
            }

            // in-wave reduce over the wave's 4 kg-chunks (lanes xor 16, 32)
#pragma unroll
            for (int r = 0; r < 8; ++r) {
                f32x4 a = acc[r];
                a.x += __shfl_xor(a.x, 16); a.y += __shfl_xor(a.y, 16);
                a.z += __shfl_xor(a.z, 16); a.w += __shfl_xor(a.w, 16);
                a.x += __shfl_xor(a.x, 32); a.y += __shfl_xor(a.y, 32);
                a.z += __shfl_xor(a.z, 32); a.w += __shfl_xor(a.w, 32);
                acc[r] = a;
            }
            if ((tid & 48) == 0) {
#pragma unroll
                for (int r = 0; r < 8; ++r)
                    *(f32x4*)&sm[OFF_PART + ((l * 2 + w2) * 8 + r) * Bsz + b4w] = acc[r];
            }
            __syncthreads();

            // stage A: 2048 gate values (4 per thread)
#pragma unroll
            for (int it = 0; it < 4; ++it) {
                const int idx = it * NTHR + tid;
                const int la = idx >> 9, r = (idx >> 6) & 7, b = idx & 63;
                float v = sm[OFF_BS + la * 8 + r]
                        + sm[OFF_PART + ((la * 2 + 0) * 8 + r) * Bsz + b]
                        + sm[OFF_PART + ((la * 2 + 1) * 8 + r) * Bsz + b];
                if (la == 0 && s < Tn)
                    v = fmaf(iput[b * Tn + s], sm[OFF_W0 + r], v);
                sm[OFF_GSUM + idx] = v;
            }
            __syncthreads();

            // stage B: one cell element per thread (4 layers x 2 cols x 64 b)
            {
                const int lb = tid >> 7, jl = (tid >> 6) & 1, b = tid & 63;
                const int tb = s - lb;
                if ((unsigned)tb < (unsigned)Tn) {
                    const int jg = bi * 2 + jl;
                    const float* gs = sm + OFF_GSUM + lb * 512 + (jl << 2) * 64;
                    const float i_ = sigm(gs[0 * 64 + b]);
                    const float f_ = sigm(gs[1 * 64 + b]);
                    const float g_ = tanhf(gs[2 * 64 + b]);
                    const float o_ = sigm(gs[3 * 64 + b]);
                    float* cp = sm + OFF_C + (lb * 2 + jl) * Bsz + b;
                    const float c2 = fmaf(f_, *cp, i_ * g_);
                    *cp = c2;
                    const float h2 = o_ * tanhf(c2);
                    GSTF(&cur[((size_t)lb * Hn + jg) * Bsz + b], h2);
                    if (lb == 3)
                        GSTF(&g_hist[((size_t)tb * Hn + jg) * Bsz + b], h2);
                }
            }
            gbar(wsb, tid, x, cnt_x, e);
        }
    }

    // ============ batched readout of out[:,0..255] + parity consolidation ====
    {
        const int b = tid & 63, jq = tid >> 6;
        const float* hp = g_hist + ((size_t)bi * Hn + jq * 64) * Bsz + b;
        const float* wp = sm + OFF_WLIN + jq * 64;
        float r = 0.0f;
#pragma unroll 8
        for (int j = 0; j < 64; ++j) r = fmaf(hp[j * Bsz], wp[j], r);
        sm[OFF_RP + jq * Bsz + b] = r;
        // copy h_l(255) for l=1,3 from parity-0 buffer into parity-1 buffer
        if (tid < 256) {
            const int li = (tid >> 7) * 2 + 1;          // 1 or 3
            const int jl = (tid >> 6) & 1, bb = tid & 63;
            const size_t o = ((size_t)li * Hn + bi * 2 + jl) * Bsz + bb;
            const float v = g_h[o];
            GSTF(&g_h[LHB + o], v);
        }
        __syncthreads();
        if (tid < Bsz) {
            float xx = blin0;
#pragma unroll
            for (int q = 0; q < 8; ++q) xx += sm[OFF_RP + q * Bsz + tid];
            out[tid * TTn + bi] = xx;
            if (bi == 255) GSTF(&g_xsg[tid], xx);
        }
        gbar(wsb, tid, x, cnt_x, e);
    }

    // ============ future phase: serial 4-layer chain + folded readout =======
    {
        const int bg  = tid & 15, b4 = bg * 4;
        const int kg  = tid >> 4;        // 0..31, chunk of 16 k
        const int k0  = kg * 16;
        const int wv_ = tid >> 6;

        for (int t = Tn; t < TTn; ++t) {
            const int ci = t & 1;
            float* hcur        = g_h + ci * LHB;
            const float* hprev = g_h + (ci ^ 1) * LHB;

            for (int lyr = 0; lyr < Ln; ++lyr) {
                // x for this t: wave 0 sums distributed partials (overlaps GEMM)
                if (lyr == 0 && tid < Bsz) {
                    float xx;
                    if (t == Tn) {
                        xx = g_xsg[tid];
                    } else {
                        const f32x4* pp2 = (const f32x4*)(g_p + tid * NBLK);
                        f32x4 s4 = {0.f, 0.f, 0.f, 0.f};
#pragma unroll 16
                        for (int q = 0; q < NBLK / 4; ++q) s4 += pp2[q];
                        xx = s4.x + s4.y + s4.z + s4.w + blin0;
                        if (bi == ((t - 1) & 255))
                            out[tid * TTn + (t - 1)] = xx;
                    }
                    sm[OFF_XS + tid] = xx;
                }

                f32x4 acc[8];
#pragma unroll
                for (int r = 0; r < 8; ++r) acc[r] = (f32x4){0.f, 0.f, 0.f, 0.f};

                if (lyr > 0)
                    gemm16(sm + OFF_WIH + (lyr - 1) * 8 * Hn,
                           hcur + (size_t)(lyr - 1) * HB, k0, b4, acc);
                gemm16(sm + OFF_WHH + lyr * 8 * Hn,
                       hprev + (size_t)lyr * HB, k0, b4, acc);

#pragma unroll
                for (int r = 0; r < 8; ++r) {
                    f32x4 a = acc[r];
                    a.x += __shfl_xor(a.x, 16); a.y += __shfl_xor(a.y, 16);
                    a.z += __shfl_xor(a.z, 16); a.w += __shfl_xor(a.w, 16);
                    a.x += __shfl_xor(a.x, 32); a.y += __shfl_xor(a.y, 32);
                    a.z += __shfl_xor(a.z, 32); a.w += __shfl_xor(a.w, 32);
                    acc[r] = a;
                }
                if ((tid & 48) == 0) {
#pragma unroll
                    for (int r = 0; r < 8; ++r)
                        *(f32x4*)&sm[OFF_PART + (wv_ * 8 + r) * Bsz + b4] = acc[r];
                }
                __syncthreads();

                {   // stage A: one gate value per thread
                    const int r = tid >> 6, b = tid & 63;
                    float v = sm[OFF_BS + lyr * 8 + r];
#pragma unroll
                    for (int q = 0; q < 8; ++q)
                        v += sm[OFF_PART + (q * 8 + r) * Bsz + b];
                    if (lyr == 0)
                        v = fmaf(sm[OFF_XS + b], sm[OFF_W0 + r], v);
                    sm[OFF_GSUM + tid] = v;
                }
                __syncthreads();

                // stage B
                float h2 = 0.0f;
                if (tid < 128) {
                    const int jl = tid >> 6, b = tid & 63;
                    const int jg = bi * 2 + jl;
                    const float* gs = sm + OFF_GSUM + jl * 4 * Bsz;
                    const float i_ = sigm(gs[0 * Bsz + b]);
                    const float f_ = sigm(gs[1 * Bsz + b]);
                    const float g_ = tanhf(gs[2 * Bsz + b]);
                    const float o_ = sigm(gs[3 * Bsz + b]);
                    float* cp = sm + OFF_C + (lyr * 2 + jl) * Bsz + b;
                    const float c2 = fmaf(f_, *cp, i_ * g_);
                    *cp = c2;
                    h2 = o_ * tanhf(c2);
                    GSTF(&hcur[((size_t)lyr * Hn + jg) * Bsz + b], h2);
                    if (lyr == 3 && jl == 1)
                        sm[OFF_RP + b] = h2 * sm[OFF_WLIN + jg];
                }
                __syncthreads();
                if (lyr == 3 && tid < Bsz) {
                    const float pv = fmaf(h2, sm[OFF_WLIN + bi * 2], sm[OFF_RP + tid]);
                    GSTF(&g_p[tid * NBLK + bi], pv);
                }

                gbar(wsb, tid, x, cnt_x, e);
            }
        }
    }

    // ---- final readout out[:,319]
    if (bi == 0 && tid < Bsz) {
        const f32x4* pp2 = (const f32x4*)(g_p + tid * NBLK);
        f32x4 s4 = {0.f, 0.f, 0.f, 0.f};
#pragma unroll 16
        for (int q = 0; q < NBLK / 4; ++q) s4 += pp2[q];
        out[tid * TTn + (TTn - 1)] = s4.x + s4.y + s4.z + s4.w + blin0;
    }
}

extern "C" void kernel_launch(void* const* d_in, const int* in_sizes, int n_in,
                              void* d_out, int out_size, void* d_ws, size_t ws_size,
                              hipStream_t stream) {
    const float* iput = (const float*)d_in[0];
    const float* Wih0 = (const float*)d_in[1];
    const float* Wih  = (const float*)d_in[2];
    const float* Whh  = (const float*)d_in[3];
    const float* bih  = (const float*)d_in[4];
    const float* bhh  = (const float*)d_in[5];
    const float* Wlin = (const float*)d_in[6];
    const float* blin = (const float*)d_in[7];
    float* out = (float*)d_out;
    uint32_t* wsb = (uint32_t*)d_ws;

    (void)hipFuncSetAttribute((const void*)lstm_seq,
                              hipFuncAttributeMaxDynamicSharedMemorySize, SMEM_BYTES);

    // zero barrier state each launch (graph-capturable async memset)
    (void)hipMemsetAsync(d_ws, 0, WS_U32S * sizeof(uint32_t), stream);

    void* args[] = {&iput, &Wih0, &Wih, &Whh, &bih, &bhh, &Wlin, &blin, &out, &wsb};
    hipLaunchCooperativeKernel((const void*)lstm_seq, dim3(NBLK), dim3(NTHR), args,
                               SMEM_BYTES, stream);
}

// Round 10
// 9005.379 us; speedup vs baseline: 7.5036x; 1.0783x over previous
//
#include <hip/hip_runtime.h>

#define Bsz 64
#define Tn 256
#define Hn 512
#define Ln 4
#define Gn 2048
#define TTn 320
#define NBLK 256
#define NTHR 512
#define HB (Hn * Bsz)
#define LHB (Ln * HB)
#define NPH_W (Tn + Ln - 1)   // 259 diagonal warmup phases

typedef float f32x4 __attribute__((ext_vector_type(4)));

// ---- LDS layout (float offsets) ----
#define OFF_WHH  0                                // [4][8][512]
#define OFF_WIH  (OFF_WHH + Ln * 8 * Hn)          // [3][8][512]
#define OFF_PART (OFF_WIH + (Ln - 1) * 8 * Hn)    // warmup [4][2][8][64] / future [8][8][64]
#define OFF_GSUM (OFF_PART + 8 * 8 * Bsz)         // warmup [4][8][64] / future [8][64]
#define OFF_BS   (OFF_GSUM + Ln * 8 * Bsz)        // [4][8]
#define OFF_W0   (OFF_BS + Ln * 8)                // [8]
#define OFF_WLIN (OFF_W0 + 8)                     // [512]
#define OFF_RP   (OFF_WLIN + Hn)                  // [8][64]
#define OFF_XS   (OFF_RP + 8 * Bsz)               // [64]
#define OFF_C    (OFF_XS + Bsz)                   // [4][2][64]
#define SMEM_FLOATS (OFF_C + Ln * 2 * Bsz)
#define SMEM_BYTES (SMEM_FLOATS * 4)              // ~142.4 KB

// ---- workspace (u32; zeroed by hipMemsetAsync each launch) ----
#define WS_BCOUNT   0                    // [16] blocks per XCD (discovery)
#define WS_ARRIVE   16                   // [16][32] per-XCD arrival ctrs (spaced)
#define WS_INVD     (16 + 16 * 32)       // [16][32] per-XCD inv-done ctrs (spaced)
#define WS_MASTER   (16 + 32 * 32)
#define WS_FLAG     (WS_MASTER + 32)
#define WS_BOOT     (WS_FLAG + 32)
#define WS_BOOTFLAG (WS_BOOT + 32)
#define WS_U32S     (WS_BOOTFLAG + 32)

__device__ float g_h[2 * LHB];        // h double-buffered by phase/t parity
__device__ float g_hist[Tn * HB];     // h3 history for batched warmup readout
__device__ float g_p[Bsz * NBLK];     // distributed readout partials [b][block]
__device__ float g_xsg[Bsz];          // x seed for t=256

__device__ __forceinline__ float sigm(float x) { return 1.0f / (1.0f + expf(-x)); }

__device__ __forceinline__ void fma4v(f32x4& a, const f32x4 h, const float w) {
    a.x = fmaf(h.x, w, a.x); a.y = fmaf(h.y, w, a.y);
    a.z = fmaf(h.z, w, a.z); a.w = fmaf(h.w, w, a.w);
}

// write-through store toward the L3 coherence point (R9-proven path).
#define GSTF(ptr, val) \
    asm volatile("global_store_dword %0, %1, off sc0 sc1" \
                 :: "v"(ptr), "v"(val) : "memory")
#define VMWAIT() asm volatile("s_waitcnt vmcnt(0)" ::: "memory")
// L1-only invalidate of THIS CU's vector cache (sc1 would add the L2 walk).
#define L1INV() asm volatile("buffer_inv" ::: "memory")

__device__ __forceinline__ uint32_t rmw_add(uint32_t* p, uint32_t v) {
    return __hip_atomic_fetch_add(p, v, __ATOMIC_RELAXED, __HIP_MEMORY_SCOPE_AGENT);
}
__device__ __forceinline__ uint32_t ald(const uint32_t* p) {
    return __hip_atomic_load(p, __ATOMIC_RELAXED, __HIP_MEMORY_SCOPE_AGENT);
}
__device__ __forceinline__ uint32_t xcc_id() {
    uint32_t x;
    asm("s_getreg_b32 %0, hwreg(HW_REG_XCC_ID)" : "=s"(x));
    return x & 15u;
}

// Bootstrap barrier (once): per-block release+acquire, counts blocks per XCD.
__device__ __forceinline__ void boot_bar(uint32_t* wsb, int tid) {
    VMWAIT();
    __syncthreads();
    if (tid == 0) {
        __builtin_amdgcn_fence(__ATOMIC_RELEASE, "agent");
        uint32_t old = rmw_add(wsb + WS_BOOT, 1u);
        if (old == NBLK - 1u) rmw_add(wsb + WS_BOOTFLAG, 1u);
        while (ald(wsb + WS_BOOTFLAG) < 1u) __builtin_amdgcn_s_sleep(2);
        __builtin_amdgcn_fence(__ATOMIC_ACQUIRE, "agent");
    }
    __syncthreads();
    asm volatile("" ::: "memory");
}

// Grid barrier v10: leader-only RELEASE (one wbl2/XCD) and leader-only L2
// ACQUIRE (one inv/XCD), with per-block L1-only invalidate by the 31 peers
// AFTER the leader's L2-inv (so L1 refills hit clean L2). The per-CU L1 inv
// is the piece a leader cannot do for its peers (R7's failure; R9's fix).
__device__ __forceinline__ void gbar(uint32_t* wsb, int tid, uint32_t x,
                                     uint32_t cnt_x, uint32_t& e) {
    ++e;
    VMWAIT();          // drain write-through stores before arriving
    __syncthreads();
    if (tid == 0) {
        uint32_t old = rmw_add(wsb + WS_ARRIVE + x * 32, 1u);
        if (old == e * cnt_x - 1u) {            // leader: last arriver on XCD
            __builtin_amdgcn_fence(__ATOMIC_RELEASE, "agent");  // one wbl2/XCD
            uint32_t m = rmw_add(wsb + WS_MASTER, cnt_x);
            if (m + cnt_x == e * (uint32_t)NBLK)
                rmw_add(wsb + WS_FLAG, 1u);     // last XCD: open the gate
            while (ald(wsb + WS_FLAG) < e) __builtin_amdgcn_s_sleep(1);
            __builtin_amdgcn_fence(__ATOMIC_ACQUIRE, "agent");  // inv L1+L2
            rmw_add(wsb + WS_INVD + x * 32, 1u);
        } else {                                // peer: wait for L2 clean,
            while (ald(wsb + WS_INVD + x * 32) < e) __builtin_amdgcn_s_sleep(1);
            L1INV();                            // then invalidate own L1
            VMWAIT();
        }
    }
    __syncthreads();
    asm volatile("" ::: "memory");
}

// Future-section partial GEMM: thread's 16-k chunk, plain loads.
__device__ __forceinline__ void gemm16(const float* __restrict__ w,     // LDS [8][512]
                                       const float* __restrict__ hbase, // global [512][64]
                                       int k0, int b4, f32x4* acc) {
#pragma unroll
    for (int c = 0; c < 4; ++c) {
        const int k = k0 + c * 4;
        const float* hp = hbase + (size_t)k * Bsz + b4;
        const f32x4 h0 = *(const f32x4*)(hp);
        const f32x4 h1 = *(const f32x4*)(hp + Bsz);
        const f32x4 h2 = *(const f32x4*)(hp + 2 * Bsz);
        const f32x4 h3 = *(const f32x4*)(hp + 3 * Bsz);
#pragma unroll
        for (int r = 0; r < 8; ++r) {
            const f32x4 wv = *(const f32x4*)(w + r * Hn + k);
            fma4v(acc[r], h0, wv.x); fma4v(acc[r], h1, wv.y);
            fma4v(acc[r], h2, wv.z); fma4v(acc[r], h3, wv.w);
        }
    }
}

__global__ __launch_bounds__(NTHR, 1)
void lstm_seq(const float* __restrict__ iput,   // [B][T]
              const float* __restrict__ Wih0,   // [2048]
              const float* __restrict__ Wih,    // [3][2048][512]
              const float* __restrict__ Whh,    // [4][2048][512]
              const float* __restrict__ bih,    // [4][2048]
              const float* __restrict__ bhh,    // [4][2048]
              const float* __restrict__ Wlin,   // [512]
              const float* __restrict__ blin,   // [1]
              float* __restrict__ out,          // [B][320]
              uint32_t* __restrict__ wsb)       // barrier state (zeroed)
{
    extern __shared__ float sm[];
    const int bi  = blockIdx.x;
    const int tid = threadIdx.x;
    uint32_t e = 0;

    const uint32_t x = xcc_id();
    uint32_t cnt_x = 0;
    if (tid == 0) rmw_add(wsb + WS_BCOUNT + x, 1u);   // discovery

    // ---- stage weights into LDS (row r=(jl<<2)|q -> gate row q*512+bi*2+jl)
    for (int i = tid; i < Ln * 8 * Hn; i += NTHR) {
        const int lyr = i >> 12, rem = i & 4095, r = rem >> 9, k = rem & 511;
        sm[OFF_WHH + i] = Whh[((size_t)(lyr * Gn + (r & 3) * Hn + bi * 2 + (r >> 2))) * Hn + k];
    }
    for (int i = tid; i < (Ln - 1) * 8 * Hn; i += NTHR) {
        const int lyr = i >> 12, rem = i & 4095, r = rem >> 9, k = rem & 511;
        sm[OFF_WIH + i] = Wih[((size_t)(lyr * Gn + (r & 3) * Hn + bi * 2 + (r >> 2))) * Hn + k];
    }
    if (tid < Ln * 8) {
        const int lyr = tid >> 3, r = tid & 7;
        const int gg = lyr * Gn + (r & 3) * Hn + bi * 2 + (r >> 2);
        sm[OFF_BS + tid] = bih[gg] + bhh[gg];
    }
    if (tid < 8) sm[OFF_W0 + tid] = Wih0[(tid & 3) * Hn + bi * 2 + (tid >> 2)];
    for (int i = tid; i < Hn; i += NTHR) sm[OFF_WLIN + i] = Wlin[i];
    for (int i = tid; i < Ln * 2 * Bsz; i += NTHR) sm[OFF_C + i] = 0.0f;

    // zero persistent h (write-through; boot_bar release covers either way)
    for (int i = bi * NTHR + tid; i < 2 * LHB; i += NBLK * NTHR)
        GSTF(&g_h[i], 0.0f);

    const float blin0 = blin[0];
    boot_bar(wsb, tid);
    if (tid == 0) cnt_x = ald(wsb + WS_BCOUNT + x);   // final per-XCD count

    // ============ warmup: diagonal wavefront, 1 barrier per phase ============
    // phase s: layer l computes t = s - l (active iff 0 <= t < 256).
    {
        const int l   = tid >> 7;        // this thread's layer 0..3
        const int sub = tid & 127;
        const int bgw = sub & 15, b4w = bgw * 4;
        const int kgw = sub >> 4;        // 0..7, k-chunk of 64
        const int k0w = kgw * 64;
        const int w2  = (tid >> 6) & 1;  // wave-within-layer

        for (int s = 0; s < NPH_W; ++s) {
            const int pp = s & 1;
            float* cur        = g_h + pp * LHB;
            const float* prev = g_h + (pp ^ 1) * LHB;
            const int t = s - l;
            const bool act = ((unsigned)t < (unsigned)Tn);

            f32x4 acc[8];
#pragma unroll
            for (int r = 0; r < 8; ++r) acc[r] = (f32x4){0.f, 0.f, 0.f, 0.f};

            if (act) {
                {   // hidden-hidden: h_l(t-1) = prev[l]
                    const float* wh  = sm + OFF_WHH + l * 8 * Hn;
                    const float* hp0 = prev + (size_t)l * HB;
#pragma unroll 4
                    for (int c = 0; c < 16; ++c) {
                        const int k = k0w + (((c + (kgw & 3) * 4) & 15) << 2);
                        const float* hp = hp0 + (size_t)k * Bsz + b4w;
                        const f32x4 h0 = *(const f32x4*)(hp);
                        const f32x4 h1 = *(const f32x4*)(hp + Bsz);
                        const f32x4 h2 = *(const f32x4*)(hp + 2 * Bsz);
                        const f32x4 h3 = *(const f32x4*)(hp + 3 * Bsz);
#pragma unroll
                        for (int r = 0; r < 8; ++r) {
                            const f32x4 wv = *(const f32x4*)(wh + r * Hn + k);
                            fma4v(acc[r], h0, wv.x); fma4v(acc[r], h1, wv.y);
                            fma4v(acc[r], h2, wv.z); fma4v(acc[r], h3, wv.w);
                        }
                    }
                }
                if (l > 0) {   // input: h_{l-1}(t) = prev[l-1]
                    const float* wh  = sm + OFF_WIH + (l - 1) * 8 * Hn;
                    const float* hp0 = prev + (size_t)(l - 1) * HB;
#pragma unroll 4
                    for (int c = 0; c < 16; ++c) {
                        const int k = k0w + (((c + (kgw & 3) * 4) & 15) << 2);
                        const float* hp = hp0 + (size_t)k * Bsz + b4w;
                        const f32x4 h0 = *(const f32x4*)(hp);
                        const f32x4 h1 = *(const f32x4*)(hp + Bsz);
                        const f32x4 h2 = *(const f32x4*)(hp + 2 * Bsz);
                        const f32x4 h3 = *(const f32x4*)(hp + 3 * Bsz);
#pragma unroll
                        for (int r = 0; r < 8; ++r) {
                            const f32x4 wv = *(const f32x4*)(wh + r * Hn + k);
                            fma4v(acc[r], h0, wv.x); fma4v(acc[r], h1, wv.y);
                            fma4v(acc[r], h2, wv.z); fma4v(acc[r], h3, wv.w);
                        }
                    }
                }
            }

            // in-wave reduce over the wave's 4 kg-chunks (lanes xor 16, 32)
#pragma unroll
            for (int r = 0; r < 8; ++r) {
                f32x4 a = acc[r];
                a.x += __shfl_xor(a.x, 16); a.y += __shfl_xor(a.y, 16);
                a.z += __shfl_xor(a.z, 16); a.w += __shfl_xor(a.w, 16);
                a.x += __shfl_xor(a.x, 32); a.y += __shfl_xor(a.y, 32);
                a.z += __shfl_xor(a.z, 32); a.w += __shfl_xor(a.w, 32);
                acc[r] = a;
            }
            if ((tid & 48) == 0) {
#pragma unroll
                for (int r = 0; r < 8; ++r)
                    *(f32x4*)&sm[OFF_PART + ((l * 2 + w2) * 8 + r) * Bsz + b4w] = acc[r];
            }
            __syncthreads();

            // stage A: 2048 gate values (4 per thread)
#pragma unroll
            for (int it = 0; it < 4; ++it) {
                const int idx = it * NTHR + tid;
                const int la = idx >> 9, r = (idx >> 6) & 7, b = idx & 63;
                float v = sm[OFF_BS + la * 8 + r]
                        + sm[OFF_PART + ((la * 2 + 0) * 8 + r) * Bsz + b]
                        + sm[OFF_PART + ((la * 2 + 1) * 8 + r) * Bsz + b];
                if (la == 0 && s < Tn)
                    v = fmaf(iput[b * Tn + s], sm[OFF_W0 + r], v);
                sm[OFF_GSUM + idx] = v;
            }
            __syncthreads();

            // stage B: one cell element per thread (4 layers x 2 cols x 64 b)
            {
                const int lb = tid >> 7, jl = (tid >> 6) & 1, b = tid & 63;
                const int tb = s - lb;
                if ((unsigned)tb < (unsigned)Tn) {
                    const int jg = bi * 2 + jl;
                    const float* gs = sm + OFF_GSUM + lb * 512 + (jl << 2) * 64;
                    const float i_ = sigm(gs[0 * 64 + b]);
                    const float f_ = sigm(gs[1 * 64 + b]);
                    const float g_ = tanhf(gs[2 * 64 + b]);
                    const float o_ = sigm(gs[3 * 64 + b]);
                    float* cp = sm + OFF_C + (lb * 2 + jl) * Bsz + b;
                    const float c2 = fmaf(f_, *cp, i_ * g_);
                    *cp = c2;
                    const float h2 = o_ * tanhf(c2);
                    GSTF(&cur[((size_t)lb * Hn + jg) * Bsz + b], h2);
                    if (lb == 3)
                        GSTF(&g_hist[((size_t)tb * Hn + jg) * Bsz + b], h2);
                }
            }
            gbar(wsb, tid, x, cnt_x, e);
        }
    }

    // ============ batched readout of out[:,0..255] + parity consolidation ====
    {
        const int b = tid & 63, jq = tid >> 6;
        const float* hp = g_hist + ((size_t)bi * Hn + jq * 64) * Bsz + b;
        const float* wp = sm + OFF_WLIN + jq * 64;
        float r = 0.0f;
#pragma unroll 8
        for (int j = 0; j < 64; ++j) r = fmaf(hp[j * Bsz], wp[j], r);
        sm[OFF_RP + jq * Bsz + b] = r;
        // copy h_l(255) for l=1,3 from parity-0 buffer into parity-1 buffer
        if (tid < 256) {
            const int li = (tid >> 7) * 2 + 1;          // 1 or 3
            const int jl = (tid >> 6) & 1, bb = tid & 63;
            const size_t o = ((size_t)li * Hn + bi * 2 + jl) * Bsz + bb;
            const float v = g_h[o];
            GSTF(&g_h[LHB + o], v);
        }
        __syncthreads();
        if (tid < Bsz) {
            float xx = blin0;
#pragma unroll
            for (int q = 0; q < 8; ++q) xx += sm[OFF_RP + q * Bsz + tid];
            out[tid * TTn + bi] = xx;
            if (bi == 255) GSTF(&g_xsg[tid], xx);
        }
        gbar(wsb, tid, x, cnt_x, e);
    }

    // ============ future phase: serial 4-layer chain + folded readout =======
    {
        const int bg  = tid & 15, b4 = bg * 4;
        const int kg  = tid >> 4;        // 0..31, chunk of 16 k
        const int k0  = kg * 16;
        const int wv_ = tid >> 6;

        for (int t = Tn; t < TTn; ++t) {
            const int ci = t & 1;
            float* hcur        = g_h + ci * LHB;
            const float* hprev = g_h + (ci ^ 1) * LHB;

            for (int lyr = 0; lyr < Ln; ++lyr) {
                // x for this t: wave 0 sums distributed partials (overlaps GEMM)
                if (lyr == 0 && tid < Bsz) {
                    float xx;
                    if (t == Tn) {
                        xx = g_xsg[tid];
                    } else {
                        const f32x4* pp2 = (const f32x4*)(g_p + tid * NBLK);
                        f32x4 s4 = {0.f, 0.f, 0.f, 0.f};
#pragma unroll 16
                        for (int q = 0; q < NBLK / 4; ++q) s4 += pp2[q];
                        xx = s4.x + s4.y + s4.z + s4.w + blin0;
                        if (bi == ((t - 1) & 255))
                            out[tid * TTn + (t - 1)] = xx;
                    }
                    sm[OFF_XS + tid] = xx;
                }

                f32x4 acc[8];
#pragma unroll
                for (int r = 0; r < 8; ++r) acc[r] = (f32x4){0.f, 0.f, 0.f, 0.f};

                if (lyr > 0)
                    gemm16(sm + OFF_WIH + (lyr - 1) * 8 * Hn,
                           hcur + (size_t)(lyr - 1) * HB, k0, b4, acc);
                gemm16(sm + OFF_WHH + lyr * 8 * Hn,
                       hprev + (size_t)lyr * HB, k0, b4, acc);

#pragma unroll
                for (int r = 0; r < 8; ++r) {
                    f32x4 a = acc[r];
                    a.x += __shfl_xor(a.x, 16); a.y += __shfl_xor(a.y, 16);
                    a.z += __shfl_xor(a.z, 16); a.w += __shfl_xor(a.w, 16);
                    a.x += __shfl_xor(a.x, 32); a.y += __shfl_xor(a.y, 32);
                    a.z += __shfl_xor(a.z, 32); a.w += __shfl_xor(a.w, 32);
                    acc[r] = a;
                }
                if ((tid & 48) == 0) {
#pragma unroll
                    for (int r = 0; r < 8; ++r)
                        *(f32x4*)&sm[OFF_PART + (wv_ * 8 + r) * Bsz + b4] = acc[r];
                }
                __syncthreads();

                {   // stage A: one gate value per thread
                    const int r = tid >> 6, b = tid & 63;
                    float v = sm[OFF_BS + lyr * 8 + r];
#pragma unroll
                    for (int q = 0; q < 8; ++q)
                        v += sm[OFF_PART + (q * 8 + r) * Bsz + b];
                    if (lyr == 0)
                        v = fmaf(sm[OFF_XS + b], sm[OFF_W0 + r], v);
                    sm[OFF_GSUM + tid] = v;
                }
                __syncthreads();

                // stage B
                float h2 = 0.0f;
                if (tid < 128) {
                    const int jl = tid >> 6, b = tid & 63;
                    const int jg = bi * 2 + jl;
                    const float* gs = sm + OFF_GSUM + jl * 4 * Bsz;
                    const float i_ = sigm(gs[0 * Bsz + b]);
                    const float f_ = sigm(gs[1 * Bsz + b]);
                    const float g_ = tanhf(gs[2 * Bsz + b]);
                    const float o_ = sigm(gs[3 * Bsz + b]);
                    float* cp = sm + OFF_C + (lyr * 2 + jl) * Bsz + b;
                    const float c2 = fmaf(f_, *cp, i_ * g_);
                    *cp = c2;
                    h2 = o_ * tanhf(c2);
                    GSTF(&hcur[((size_t)lyr * Hn + jg) * Bsz + b], h2);
                    if (lyr == 3 && jl == 1)
                        sm[OFF_RP + b] = h2 * sm[OFF_WLIN + jg];
                }
                __syncthreads();
                if (lyr == 3 && tid < Bsz) {
                    const float pv = fmaf(h2, sm[OFF_WLIN + bi * 2], sm[OFF_RP + tid]);
                    GSTF(&g_p[tid * NBLK + bi], pv);
                }

                gbar(wsb, tid, x, cnt_x, e);
            }
        }
    }

    // ---- final readout out[:,319]
    if (bi == 0 && tid < Bsz) {
        const f32x4* pp2 = (const f32x4*)(g_p + tid * NBLK);
        f32x4 s4 = {0.f, 0.f, 0.f, 0.f};
#pragma unroll 16
        for (int q = 0; q < NBLK / 4; ++q) s4 += pp2[q];
        out[tid * TTn + (TTn - 1)] = s4.x + s4.y + s4.z + s4.w + blin0;
    }
}

extern "C" void kernel_launch(void* const* d_in, const int* in_sizes, int n_in,
                              void* d_out, int out_size, void* d_ws, size_t ws_size,
                              hipStream_t stream) {
    const float* iput = (const float*)d_in[0];
    const float* Wih0 = (const float*)d_in[1];
    const float* Wih  = (const float*)d_in[2];
    const float* Whh  = (const float*)d_in[3];
    const float* bih  = (const float*)d_in[4];
    const float* bhh  = (const float*)d_in[5];
    const float* Wlin = (const float*)d_in[6];
    const float* blin = (const float*)d_in[7];
    float* out = (float*)d_out;
    uint32_t* wsb = (uint32_t*)d_ws;

    (void)hipFuncSetAttribute((const void*)lstm_seq,
                              hipFuncAttributeMaxDynamicSharedMemorySize, SMEM_BYTES);

    // zero barrier state each launch (graph-capturable async memset)
    (void)hipMemsetAsync(d_ws, 0, WS_U32S * sizeof(uint32_t), stream);

    void* args[] = {&iput, &Wih0, &Wih, &Whh, &bih, &bhh, &Wlin, &blin, &out, &wsb};
    hipLaunchCooperativeKernel((const void*)lstm_seq, dim3(NBLK), dim3(NTHR), args,
                               SMEM_BYTES, stream);
}